// Round 3
// baseline (1895.798 us; speedup 1.0000x reference)
//
#include <hip/hip_runtime.h>
#include <math.h>

#define NSEQ 320
#define HDIM 512
#define G4   2048
#define EMBD 300
#define ELMOD 1024
#define XPAD 832          // 812 padded to multiple of 32

typedef __attribute__((ext_vector_type(8))) short bf16x8;
typedef __attribute__((ext_vector_type(4))) float f32x4;
typedef unsigned short ushort_t;

__device__ __forceinline__ float sigmoidf_(float x) { return 1.0f / (1.0f + expf(-x)); }

__device__ __forceinline__ ushort_t f2bf(float f) {
    unsigned u = __float_as_uint(f);
    u = (u + 0x7FFFu + ((u >> 16) & 1u)) >> 16;   // RNE
    return (ushort_t)u;
}
__device__ __forceinline__ float bf2f(ushort_t u) {
    return __uint_as_float(((unsigned)u) << 16);
}
__device__ __forceinline__ unsigned pack2(float a, float b) {
    return (unsigned)f2bf(a) | ((unsigned)f2bf(b) << 16);
}

// ---------------- fp32 -> bf16 weight conversion (with zero pad / offset) ----------------
__global__ __launch_bounds__(256) void conv_bf16_kernel(
    const float* __restrict__ src, int srcCols,
    ushort_t* __restrict__ dst, int dstStride, int dstOff,
    int fillCols)
{
    int c = blockIdx.x * 256 + threadIdx.x;
    int r = blockIdx.y;
    if (c >= fillCols) return;
    float v = (c < srcCols) ? src[(size_t)r * srcCols + c] : 0.0f;
    dst[(size_t)r * dstStride + dstOff + c] = f2bf(v);
}

// ---------------- GloVe gather -> Xb[:,0:300] bf16, zero pad cols [812,832) ----------------
__global__ __launch_bounds__(128) void emb_gather_kernel(
    const int* __restrict__ tok, const float* __restrict__ w_emb,
    ushort_t* __restrict__ Xb)
{
    int n = blockIdx.x;
    int t = threadIdx.x;
    ushort_t* dst = Xb + (size_t)n * XPAD;
    if (t < 75) {
        const float4* src = (const float4*)(w_emb + (size_t)tok[n] * EMBD);
        float4 v = src[t];
        dst[4*t+0] = f2bf(v.x); dst[4*t+1] = f2bf(v.y);
        dst[4*t+2] = f2bf(v.z); dst[4*t+3] = f2bf(v.w);
    } else if (t >= 108) {  // 20 pad cols
        dst[812 + (t - 108)] = 0;
    }
}

// ---------------- feed-forward GEMM: C_bf16[M][N] = A[M][K] * W[N][K]^T + bias ----------------
__global__ __launch_bounds__(256) void gemm_ff_kernel(
    const ushort_t* __restrict__ Ab, const float* __restrict__ Af,
    const int* __restrict__ tok, int strideA,
    const ushort_t* __restrict__ W, const float* __restrict__ bias,
    ushort_t* __restrict__ C, int strideC, int K)
{
    __shared__ ushort_t As[64 * 40];
    __shared__ ushort_t Bs[64 * 40];
    const int m0 = blockIdx.y * 64;
    const int n0 = blockIdx.x * 64;
    const int tid = threadIdx.x;
    const int r  = tid >> 2;
    const int kq = (tid & 3) << 3;

    const ushort_t* arow_b = nullptr;
    const float*    arow_f = nullptr;
    if (Af) arow_f = Af + (size_t)tok[m0 + r] * strideA + kq;
    else    arow_b = Ab + (size_t)(m0 + r) * strideA + kq;
    const ushort_t* brow = W + (size_t)(n0 + r) * K + kq;

    const int lane = tid & 63;
    const int w = tid >> 6;
    const int wm = w & 1, wn = w >> 1;
    const int kc = (lane >> 4) << 3;

    f32x4 acc[2][2];
    #pragma unroll
    for (int f = 0; f < 2; ++f)
        #pragma unroll
        for (int g = 0; g < 2; ++g)
            acc[f][g] = (f32x4){0.f, 0.f, 0.f, 0.f};

    for (int k0 = 0; k0 < K; k0 += 32) {
        if (Af) {
            float4 v0 = ((const float4*)(arow_f + k0))[0];
            float4 v1 = ((const float4*)(arow_f + k0))[1];
            uint4 p; p.x = pack2(v0.x, v0.y); p.y = pack2(v0.z, v0.w);
            p.z = pack2(v1.x, v1.y); p.w = pack2(v1.z, v1.w);
            *(uint4*)&As[r*40 + kq] = p;
        } else {
            *(uint4*)&As[r*40 + kq] = *(const uint4*)(arow_b + k0);
        }
        *(uint4*)&Bs[r*40 + kq] = *(const uint4*)(brow + k0);
        __syncthreads();
        bf16x8 af[2], bfr[2];
        #pragma unroll
        for (int f = 0; f < 2; ++f)
            af[f] = *(const bf16x8*)&As[(wm*32 + f*16 + (lane & 15))*40 + kc];
        #pragma unroll
        for (int g = 0; g < 2; ++g)
            bfr[g] = *(const bf16x8*)&Bs[(wn*32 + g*16 + (lane & 15))*40 + kc];
        #pragma unroll
        for (int f = 0; f < 2; ++f)
            #pragma unroll
            for (int g = 0; g < 2; ++g)
                acc[f][g] = __builtin_amdgcn_mfma_f32_16x16x32_bf16(af[f], bfr[g], acc[f][g], 0, 0, 0);
        __syncthreads();
    }

    #pragma unroll
    for (int f = 0; f < 2; ++f) {
        #pragma unroll
        for (int g = 0; g < 2; ++g) {
            int col = n0 + wn*32 + g*16 + (lane & 15);
            float bv = bias[col];
            #pragma unroll
            for (int i = 0; i < 4; ++i) {
                int row = m0 + wm*32 + f*16 + ((lane >> 4) << 2) + i;
                C[(size_t)row * strideC + col] = f2bf(acc[f][g][i] + bv);
            }
        }
    }
}

// ---------------- persistent 4-cell LSTM kernel with inter-block barriers ----------------
struct PCell {
    const ushort_t* A0; const ushort_t* A1;   // acat parity buffers (lda = 1024)
    const ushort_t* B;                        // [2048][K]
    const ushort_t* xp;                       // L0: XP0 base (row n*T+t, stride 2048)
    const float* bias;                        // L1: b1
    ushort_t* O0; ushort_t* O1;               // output base (x-part or h-part), stride 1024
    float* hlast;                             // L1: fp32 dest when t == lens[n]-1
    const int* lens;
    int K, T, layer;
};
struct PPack { PCell cell[4]; };

__global__ __launch_bounds__(256) void lstm_persist_kernel(PPack P, int* ctrs)
{
    const int cellId = blockIdx.x >> 6;
    const int blk    = blockIdx.x & 63;
    const PCell c = P.cell[cellId];
    int* ctr = ctrs + (cellId >> 1) * 32;     // one counter per set, 128B apart

    const int tid  = threadIdx.x;
    const int w    = tid >> 6;
    const int lane = tid & 63;
    const int cc   = lane & 15;
    const int half = cc >> 3;
    const int jj   = cc & 7;
    const int kg   = lane >> 4;
    const int j0   = blk * 8;
    const int K    = c.K;
    const int T    = c.T;
    const int NK   = K >> 5;

    int aoff[5];
    #pragma unroll
    for (int q = 0; q < 5; ++q)
        aoff[q] = ((w*5 + q)*16 + cc) * 1024 + kg*8;
    const ushort_t* bptr0 = c.B + (size_t)((0*2 + half)*HDIM + j0 + jj) * K + kg*8;
    const ushort_t* bptr1 = c.B + (size_t)((1*2 + half)*HDIM + j0 + jj) * K + kg*8;
    const int x0col = half*HDIM + j0 + jj;
    const int x1col = 1024 + x0col;
    float bias0 = 0.f, bias1 = 0.f;
    if (c.bias) { bias0 = c.bias[x0col]; bias1 = c.bias[x1col]; }
    int lr[5][4];
    #pragma unroll
    for (int q = 0; q < 5; ++q)
        #pragma unroll
        for (int i = 0; i < 4; ++i)
            lr[q][i] = c.lens[(w*5+q)*16 + kg*4 + i];

    float creg[5][4];
    #pragma unroll
    for (int q = 0; q < 5; ++q)
        #pragma unroll
        for (int i = 0; i < 4; ++i) creg[q][i] = 0.f;

#define LOADA(buf, kk) { _Pragma("unroll") \
    for (int q = 0; q < 5; ++q) buf[q] = *(const uint4*)(Ab + aoff[q] + (kk)*32); }
#define LOADB(buf, kk) { buf[0] = *(const uint4*)(bptr0 + (size_t)(kk)*32); \
                         buf[1] = *(const uint4*)(bptr1 + (size_t)(kk)*32); }
#define MF(ab, bb) { _Pragma("unroll") \
    for (int q = 0; q < 5; ++q) { \
        acc[q][0] = __builtin_amdgcn_mfma_f32_16x16x32_bf16(*(bf16x8*)&ab[q], *(bf16x8*)&bb[0], acc[q][0], 0, 0, 0); \
        acc[q][1] = __builtin_amdgcn_mfma_f32_16x16x32_bf16(*(bf16x8*)&ab[q], *(bf16x8*)&bb[1], acc[q][1], 0, 0, 0); } }

    for (int ss = 0; ss <= T; ++ss) {
        const int par = ss & 1;
        const bool active = c.layer ? (ss >= 1) : (ss < T);
        if (active) {
            const int t = c.layer ? (ss - 1) : ss;
            const ushort_t* Ab = par ? c.A1 : c.A0;
            ushort_t* Ob       = par ? c.O0 : c.O1;   // write parity par^1

            f32x4 acc[5][2];
            #pragma unroll
            for (int q = 0; q < 5; ++q) {
                acc[q][0] = (f32x4){0.f, 0.f, 0.f, 0.f};
                acc[q][1] = (f32x4){0.f, 0.f, 0.f, 0.f};
            }
            uint4 aE[5], aO[5], bE2[2], bO2[2];
            LOADA(aE, 0); LOADB(bE2, 0);
            for (int kk = 0; kk < NK; kk += 2) {
                if (kk + 1 < NK) { LOADA(aO, kk+1); LOADB(bO2, kk+1); }
                MF(aE, bE2);
                if (kk + 2 < NK) { LOADA(aE, kk+2); LOADB(bE2, kk+2); }
                if (kk + 1 < NK) MF(aO, bO2);
            }

            #pragma unroll
            for (int q = 0; q < 5; ++q) {
                #pragma unroll
                for (int i = 0; i < 4; ++i) {
                    const int n = (w*5+q)*16 + kg*4 + i;
                    float v0 = acc[q][0][i], v1 = acc[q][1][i];
                    if (c.xp) {
                        const ushort_t* xr = c.xp + ((size_t)n * T + t) * G4;
                        v0 += bf2f(xr[x0col]); v1 += bf2f(xr[x1col]);
                    } else {
                        v0 += bias0; v1 += bias1;
                    }
                    float u0 = __shfl_xor(v0, 8);
                    float u1 = __shfl_xor(v1, 8);
                    float gi = half ? u0 : v0;
                    float gf = half ? v0 : u0;
                    float gg = half ? u1 : v1;
                    float go = half ? v1 : u1;
                    float cn = sigmoidf_(gf) * creg[q][i] + sigmoidf_(gi) * tanhf(gg);
                    creg[q][i] = cn;
                    float h = sigmoidf_(go) * tanhf(cn);
                    unsigned hb = (unsigned)f2bf(h);
                    unsigned pb = (unsigned)__shfl_xor((int)hb, 1);
                    if (half == 0 && (jj & 1) == 0)
                        *(unsigned*)(Ob + (size_t)n * 1024 + j0 + jj) = hb | (pb << 16);
                    if (c.hlast && half == 0 && t == lr[q][i] - 1)
                        c.hlast[(size_t)n * HDIM + j0 + jj] = h;
                }
            }
        }
        if (ss < T) {
            __syncthreads();
            if (tid == 0) {
                __builtin_amdgcn_fence(__ATOMIC_RELEASE, "agent");
                __hip_atomic_fetch_add(ctr, 1, __ATOMIC_RELAXED, __HIP_MEMORY_SCOPE_AGENT);
                const int tgt = 128 * (ss + 1);
                int spins = 0;
                while (__hip_atomic_load(ctr, __ATOMIC_RELAXED, __HIP_MEMORY_SCOPE_AGENT) < tgt) {
                    __builtin_amdgcn_s_sleep(2);
                    if (++spins > (1 << 18)) break;
                }
                __builtin_amdgcn_fence(__ATOMIC_ACQUIRE, "agent");
            }
            __syncthreads();
        }
    }
#undef LOADA
#undef LOADB
#undef MF
}

// ---------------- nz flags ----------------
__global__ __launch_bounds__(64) void nz_kernel(
    const float* __restrict__ he, int* __restrict__ nz)
{
    int rr = blockIdx.x;
    int lane = threadIdx.x;
    const float* row = he + (size_t)rr * HDIM;
    bool any = false;
    for (int k = lane; k < HDIM; k += 64) any |= (row[k] != 0.0f);
    unsigned long long b = __ballot(any);
    if (lane == 0) nz[rr] = (b != 0ull) ? 1 : 0;
}

// ---------------- text_rel expansion ----------------
__global__ __launch_bounds__(256) void expand_kernel(
    const float* __restrict__ he, const int* __restrict__ nz,
    float* __restrict__ out)
{
    int blk = blockIdx.x;               // ((b*10+i)*10+j)*10+k
    int k = blk % 10;
    int j = (blk / 10) % 10;
    int i = (blk / 100) % 10;
    int b = blk / 1000;
    int tid = threadIdx.x;
    float4* o = (float4*)(out + (size_t)blk * 1024);
    float4 z; z.x = z.y = z.z = z.w = 0.0f;
    if (tid < 128) {
        bool m = (j <= i) && (k <= i) && (nz[b*10 + k] != 0);
        float4 v = m ? ((const float4*)(he + (size_t)(b*10 + j) * HDIM))[tid] : z;
        o[tid] = v;
    } else {
        int c = tid - 128;
        bool m = (k <= i) && (j <= i) && (nz[b*10 + j] != 0);
        float4 v = m ? ((const float4*)(he + (size_t)(b*10 + k) * HDIM))[c] : z;
        o[128 + c] = v;
    }
}

extern "C" void kernel_launch(void* const* d_in, const int* in_sizes, int n_in,
                              void* d_out, int out_size, void* d_ws, size_t ws_size,
                              hipStream_t stream)
{
    (void)in_sizes; (void)n_in; (void)out_size; (void)ws_size;
    const int* ques     = (const int*)d_in[0];
    const int* hist     = (const int*)d_in[1];
    const int* ques_len = (const int*)d_in[2];
    const int* hist_len = (const int*)d_in[3];
    const float* w_emb  = (const float*)d_in[6];
    const float* elmo   = (const float*)d_in[7];
    const float* Wc     = (const float*)d_in[8];
    const float* bc     = (const float*)d_in[9];

    // ---- workspace layout ----
    char* ws = (char*)d_ws;
    size_t off = 0;
    auto alloc = [&](size_t bytes) { char* p = ws + off; off += (bytes + 255) & ~(size_t)255; return p; };
    ushort_t* XP0bf = (ushort_t*)alloc((size_t)19200 * G4 * 2);      // 78.6 MB
    ushort_t* Xb    = (ushort_t*)alloc((size_t)19200 * XPAD * 2);    // 32.0 MB
    ushort_t* Wcb   = (ushort_t*)alloc((size_t)HDIM * ELMOD * 2);
    ushort_t *Wih0b[2], *Whh0b[2], *Wcat[2];
    for (int s = 0; s < 2; ++s) {
        Wih0b[s] = (ushort_t*)alloc((size_t)G4 * XPAD * 2);
        Whh0b[s] = (ushort_t*)alloc((size_t)G4 * HDIM * 2);
        Wcat[s]  = (ushort_t*)alloc((size_t)G4 * ELMOD * 2);
    }
    char* state_base = ws + off;
    ushort_t* acat[2][2];
    for (int s = 0; s < 2; ++s)
        for (int p = 0; p < 2; ++p)
            acat[s][p] = (ushort_t*)alloc((size_t)NSEQ * ELMOD * 2);
    int* ctrs = (int*)alloc(256);
    size_t state_bytes = (ws + off) - state_base;
    float* he = (float*)alloc((size_t)NSEQ * HDIM * 4);
    int* nzb  = (int*)alloc(NSEQ * 4);

    float* out = (float*)d_out;
    float* ques_embed = out;
    float* text_rel   = out + (size_t)NSEQ * HDIM;

    const int rowoff[2] = {0, 6400};
    const int TT[2] = {20, 40};
    const int* toks[2] = {ques, hist};
    const int* lensp[2] = {ques_len, hist_len};

    // ---- weight conversions ----
    conv_bf16_kernel<<<dim3(4, HDIM), 256, 0, stream>>>(Wc, ELMOD, Wcb, ELMOD, 0, ELMOD);
    for (int s = 0; s < 2; ++s) {
        const float* Wih0 = (const float*)d_in[10 + 6*s];
        const float* Whh0 = (const float*)d_in[11 + 6*s];
        const float* Wih1 = (const float*)d_in[13 + 6*s];
        const float* Whh1 = (const float*)d_in[14 + 6*s];
        conv_bf16_kernel<<<dim3(4, G4), 256, 0, stream>>>(Wih0, 812, Wih0b[s], XPAD, 0, XPAD);
        conv_bf16_kernel<<<dim3(2, G4), 256, 0, stream>>>(Whh0, HDIM, Whh0b[s], HDIM, 0, HDIM);
        conv_bf16_kernel<<<dim3(2, G4), 256, 0, stream>>>(Wih1, HDIM, Wcat[s], ELMOD, 0, HDIM);
        conv_bf16_kernel<<<dim3(2, G4), 256, 0, stream>>>(Whh1, HDIM, Wcat[s], ELMOD, HDIM, HDIM);
    }

    // ---- embeddings + input projections ----
    for (int s = 0; s < 2; ++s) {
        int Ntok = NSEQ * TT[s];
        ushort_t* XbS = Xb + (size_t)rowoff[s] * XPAD;
        emb_gather_kernel<<<Ntok, 128, 0, stream>>>(toks[s], w_emb, XbS);
        gemm_ff_kernel<<<dim3(HDIM/64, Ntok/64), 256, 0, stream>>>(
            nullptr, elmo, toks[s], ELMOD, Wcb, bc, XbS + EMBD, XPAD, ELMOD);
        const float* b0 = (const float*)d_in[12 + 6*s];
        gemm_ff_kernel<<<dim3(G4/64, Ntok/64), 256, 0, stream>>>(
            XbS, nullptr, nullptr, XPAD, Wih0b[s], b0,
            XP0bf + (size_t)rowoff[s] * G4, G4, XPAD);
    }

    // ---- zero recurrent state + barrier counters ----
    hipMemsetAsync(state_base, 0, state_bytes, stream);

    // ---- persistent LSTM ----
    PPack P;
    for (int s = 0; s < 2; ++s) {
        const float* b1 = (const float*)d_in[15 + 6*s];
        PCell& c0 = P.cell[s*2 + 0];
        c0.A0 = acat[s][0]; c0.A1 = acat[s][1];
        c0.B  = Whh0b[s];
        c0.xp = XP0bf + (size_t)rowoff[s] * G4;
        c0.bias = nullptr;
        c0.O0 = acat[s][0]; c0.O1 = acat[s][1];
        c0.hlast = nullptr; c0.lens = lensp[s];
        c0.K = HDIM; c0.T = TT[s]; c0.layer = 0;
        PCell& c1 = P.cell[s*2 + 1];
        c1.A0 = acat[s][0]; c1.A1 = acat[s][1];
        c1.B  = Wcat[s];
        c1.xp = nullptr; c1.bias = b1;
        c1.O0 = acat[s][0] + HDIM; c1.O1 = acat[s][1] + HDIM;
        c1.hlast = s ? he : ques_embed;
        c1.lens = lensp[s];
        c1.K = ELMOD; c1.T = TT[s]; c1.layer = 1;
    }
    lstm_persist_kernel<<<256, 256, 0, stream>>>(P, ctrs);

    // ---- expansion ----
    nz_kernel<<<NSEQ, 64, 0, stream>>>(he, nzb);
    expand_kernel<<<32000, 256, 0, stream>>>(he, nzb, text_rel);
}

// Round 4
// 1558.480 us; speedup vs baseline: 1.2164x; 1.2164x over previous
//
#include <hip/hip_runtime.h>
#include <math.h>

#define NSEQ 320
#define HDIM 512
#define G4   2048
#define EMBD 300
#define ELMOD 1024
#define XPAD 832          // 812 padded to multiple of 32

typedef __attribute__((ext_vector_type(8))) short bf16x8;
typedef __attribute__((ext_vector_type(4))) float f32x4;
typedef unsigned short ushort_t;

__device__ __forceinline__ float sigmoidf_(float x) { return 1.0f / (1.0f + expf(-x)); }

__device__ __forceinline__ ushort_t f2bf(float f) {
    unsigned u = __float_as_uint(f);
    u = (u + 0x7FFFu + ((u >> 16) & 1u)) >> 16;   // RNE
    return (ushort_t)u;
}
__device__ __forceinline__ float bf2f(ushort_t u) {
    return __uint_as_float(((unsigned)u) << 16);
}
__device__ __forceinline__ unsigned pack2(float a, float b) {
    return (unsigned)f2bf(a) | ((unsigned)f2bf(b) << 16);
}

// ---------------- all weight conversions in ONE flat launch ----------------
struct ConvPack {
    const float* src[9];
    ushort_t* dst[9];
    int srcCols[9], dstStride[9], dstOff[9], fillCols[9];
    long base[10];
};

__global__ __launch_bounds__(256) void conv_all_kernel(ConvPack P)
{
    long gid = (long)blockIdx.x * 256 + threadIdx.x;
    if (gid >= P.base[9]) return;
    int job = 0;
    #pragma unroll
    for (int j = 1; j < 9; ++j) if (gid >= P.base[j]) job = j;
    int e  = (int)(gid - P.base[job]);
    int fc = P.fillCols[job];
    int r  = e / fc;
    int ci = e - r * fc;
    int sc = P.srcCols[job];
    float v = (ci < sc) ? P.src[job][(size_t)r * sc + ci] : 0.0f;
    P.dst[job][(size_t)r * P.dstStride[job] + P.dstOff[job] + ci] = f2bf(v);
}

// ---------------- GloVe gather (ques+hist merged) ----------------
__global__ __launch_bounds__(128) void emb_gather_kernel(
    const int* __restrict__ ques, const int* __restrict__ hist,
    const float* __restrict__ w_emb, ushort_t* __restrict__ Xb)
{
    int n = blockIdx.x;
    int tokid = (n < 6400) ? ques[n] : hist[n - 6400];
    int t = threadIdx.x;
    ushort_t* dst = Xb + (size_t)n * XPAD;
    if (t < 75) {
        const float4* src = (const float4*)(w_emb + (size_t)tokid * EMBD);
        float4 v = src[t];
        dst[4*t+0] = f2bf(v.x); dst[4*t+1] = f2bf(v.y);
        dst[4*t+2] = f2bf(v.z); dst[4*t+3] = f2bf(v.w);
    } else if (t >= 108) {  // 20 pad cols
        dst[812 + (t - 108)] = 0;
    }
}

// ---------------- feed-forward GEMM: C_bf16[M][N] = A[M][K] * W[N][K]^T + bias ----------------
__global__ __launch_bounds__(256) void gemm_ff_kernel(
    const ushort_t* __restrict__ Ab, const float* __restrict__ Af,
    const int* __restrict__ tok, int strideA,
    const ushort_t* __restrict__ W, const float* __restrict__ bias,
    ushort_t* __restrict__ C, int strideC, int K)
{
    __shared__ ushort_t As[64 * 40];
    __shared__ ushort_t Bs[64 * 40];
    const int m0 = blockIdx.y * 64;
    const int n0 = blockIdx.x * 64;
    const int tid = threadIdx.x;
    const int r  = tid >> 2;
    const int kq = (tid & 3) << 3;

    const ushort_t* arow_b = nullptr;
    const float*    arow_f = nullptr;
    if (Af) arow_f = Af + (size_t)tok[m0 + r] * strideA + kq;
    else    arow_b = Ab + (size_t)(m0 + r) * strideA + kq;
    const ushort_t* brow = W + (size_t)(n0 + r) * K + kq;

    const int lane = tid & 63;
    const int w = tid >> 6;
    const int wm = w & 1, wn = w >> 1;
    const int kc = (lane >> 4) << 3;

    f32x4 acc[2][2];
    #pragma unroll
    for (int f = 0; f < 2; ++f)
        #pragma unroll
        for (int g = 0; g < 2; ++g)
            acc[f][g] = (f32x4){0.f, 0.f, 0.f, 0.f};

    for (int k0 = 0; k0 < K; k0 += 32) {
        if (Af) {
            float4 v0 = ((const float4*)(arow_f + k0))[0];
            float4 v1 = ((const float4*)(arow_f + k0))[1];
            uint4 p; p.x = pack2(v0.x, v0.y); p.y = pack2(v0.z, v0.w);
            p.z = pack2(v1.x, v1.y); p.w = pack2(v1.z, v1.w);
            *(uint4*)&As[r*40 + kq] = p;
        } else {
            *(uint4*)&As[r*40 + kq] = *(const uint4*)(arow_b + k0);
        }
        *(uint4*)&Bs[r*40 + kq] = *(const uint4*)(brow + k0);
        __syncthreads();
        bf16x8 af[2], bfr[2];
        #pragma unroll
        for (int f = 0; f < 2; ++f)
            af[f] = *(const bf16x8*)&As[(wm*32 + f*16 + (lane & 15))*40 + kc];
        #pragma unroll
        for (int g = 0; g < 2; ++g)
            bfr[g] = *(const bf16x8*)&Bs[(wn*32 + g*16 + (lane & 15))*40 + kc];
        #pragma unroll
        for (int f = 0; f < 2; ++f)
            #pragma unroll
            for (int g = 0; g < 2; ++g)
                acc[f][g] = __builtin_amdgcn_mfma_f32_16x16x32_bf16(af[f], bfr[g], acc[f][g], 0, 0, 0);
        __syncthreads();
    }

    #pragma unroll
    for (int f = 0; f < 2; ++f) {
        #pragma unroll
        for (int g = 0; g < 2; ++g) {
            int col = n0 + wn*32 + g*16 + (lane & 15);
            float bv = bias[col];
            #pragma unroll
            for (int i = 0; i < 4; ++i) {
                int row = m0 + wm*32 + f*16 + ((lane >> 4) << 2) + i;
                C[(size_t)row * strideC + col] = f2bf(acc[f][g][i] + bv);
            }
        }
    }
}

// ---------------- persistent 4-cell LSTM: B in LDS, 128 blocks ----------------
struct PCell {
    const ushort_t* A0; const ushort_t* A1;   // acat parity buffers (lda = 1024)
    const ushort_t* B;                        // [2048][K], row = gate*512 + j
    const ushort_t* xp;                       // L0: XP0 base (row n*T+t, stride 2048)
    const float* bias;                        // L1: b1
    ushort_t* O0; ushort_t* O1;               // h dest parity (stride 1024)
    float* hlast;                             // L1: fp32 dest when t == lens[n]-1
    const int* lens;
    int K, T, layer;
};
struct PPack { PCell cell[4]; };

__global__ __launch_bounds__(256) void lstm_persist_kernel(PPack P, int* ctrs)
{
    // XCD-grouping swizzle (bijective; correctness doesn't depend on mapping)
    const int xcd    = blockIdx.x & 7;
    const int slot   = blockIdx.x >> 3;       // 0..15
    const int cellId = xcd >> 1;              // 0..3
    const int blk    = slot * 2 + (xcd & 1);  // 0..31
    const PCell c = P.cell[cellId];
    int* ctr = ctrs + (cellId >> 1) * 32;     // one counter per set

    const int tid  = threadIdx.x;
    const int w    = tid >> 6;
    const int lane = tid & 63;
    const int cc   = lane & 15;
    const int kg   = lane >> 4;
    const int j0   = blk * 16;
    const int K = c.K, T = c.T, NK = K >> 5, PK = K + 8;

    __shared__ ushort_t Bs[64 * 1032];        // 129 KB (K=1024 padded)

    // ---- preload B slice (64 rows: gate = r>>4, jj = r&15) into LDS, once ----
    {
        const int CH = K >> 3;                // 16B chunks per row
        const int tot = 64 * CH;
        for (int idx = tid; idx < tot; idx += 256) {
            int r = idx / CH, ch = idx - r * CH;
            int gr = (r >> 4) * HDIM + j0 + (r & 15);
            *(uint4*)&Bs[r * PK + ch * 8] = *(const uint4*)(c.B + (size_t)gr * K + ch * 8);
        }
    }

    int aoff[5];
    #pragma unroll
    for (int q = 0; q < 5; ++q)
        aoff[q] = ((w*5 + q)*16 + cc) * 1024 + kg*8;
    int bofs[4];
    #pragma unroll
    for (int g = 0; g < 4; ++g)
        bofs[g] = (g*16 + cc) * PK + kg*8;

    float bias_r[4] = {0.f, 0.f, 0.f, 0.f};
    if (c.bias) {
        #pragma unroll
        for (int g = 0; g < 4; ++g) bias_r[g] = c.bias[g*HDIM + j0 + cc];
    }
    int lr[5][4];
    #pragma unroll
    for (int q = 0; q < 5; ++q)
        #pragma unroll
        for (int i = 0; i < 4; ++i)
            lr[q][i] = c.lens[(w*5+q)*16 + kg*4 + i];

    float creg[5][4];
    #pragma unroll
    for (int q = 0; q < 5; ++q)
        #pragma unroll
        for (int i = 0; i < 4; ++i) creg[q][i] = 0.f;

    __syncthreads();   // B preload visible to all waves

#define LOADA(buf, kk) { _Pragma("unroll") \
    for (int q = 0; q < 5; ++q) buf[q] = *(const uint4*)(Ab + aoff[q] + (kk)*32); }
#define LOADB(buf, kk) { _Pragma("unroll") \
    for (int g = 0; g < 4; ++g) buf[g] = *(const uint4*)&Bs[bofs[g] + (kk)*32]; }
#define MF(ab, bb) { _Pragma("unroll") \
    for (int q = 0; q < 5; ++q) { _Pragma("unroll") \
        for (int g = 0; g < 4; ++g) \
            acc[q][g] = __builtin_amdgcn_mfma_f32_16x16x32_bf16(*(bf16x8*)&ab[q], *(bf16x8*)&bb[g], acc[q][g], 0, 0, 0); } }

    for (int ss = 0; ss <= T; ++ss) {
        const int par = ss & 1;
        const bool active = c.layer ? (ss >= 1) : (ss < T);
        if (active) {
            const int t = c.layer ? (ss - 1) : ss;
            const ushort_t* Ab = par ? c.A1 : c.A0;
            ushort_t* Ob       = par ? c.O0 : c.O1;   // write parity par^1

            f32x4 acc[5][4];
            #pragma unroll
            for (int q = 0; q < 5; ++q)
                #pragma unroll
                for (int g = 0; g < 4; ++g)
                    acc[q][g] = (f32x4){0.f, 0.f, 0.f, 0.f};

            uint4 aE[5], aO[5], bE[4], bO[4];
            LOADA(aE, 0); LOADB(bE, 0);
            for (int kk = 0; kk < NK; kk += 2) {
                if (kk + 1 < NK) { LOADA(aO, kk+1); LOADB(bO, kk+1); }
                MF(aE, bE);
                if (kk + 2 < NK) { LOADA(aE, kk+2); LOADB(bE, kk+2); }
                if (kk + 1 < NK) MF(aO, bO);
            }

            #pragma unroll
            for (int q = 0; q < 5; ++q) {
                #pragma unroll
                for (int i = 0; i < 4; ++i) {
                    const int n = (w*5+q)*16 + kg*4 + i;
                    const int j = j0 + cc;
                    float gi = acc[q][0][i], gf = acc[q][1][i];
                    float gg = acc[q][2][i], go = acc[q][3][i];
                    if (c.xp) {
                        const ushort_t* xr = c.xp + ((size_t)n * T + t) * G4;
                        gi += bf2f(xr[j]);          gf += bf2f(xr[HDIM + j]);
                        gg += bf2f(xr[2*HDIM + j]); go += bf2f(xr[3*HDIM + j]);
                    } else {
                        gi += bias_r[0]; gf += bias_r[1];
                        gg += bias_r[2]; go += bias_r[3];
                    }
                    float cn = sigmoidf_(gf) * creg[q][i] + sigmoidf_(gi) * tanhf(gg);
                    creg[q][i] = cn;
                    float h = sigmoidf_(go) * tanhf(cn);
                    unsigned hb = (unsigned)f2bf(h);
                    unsigned pb = (unsigned)__shfl_xor((int)hb, 1);
                    if ((cc & 1) == 0)
                        *(unsigned*)(Ob + (size_t)n * 1024 + j) = hb | (pb << 16);
                    if (c.hlast && t == lr[q][i] - 1)
                        c.hlast[(size_t)n * HDIM + j] = h;
                }
            }
        }
        if (ss < T) {
            __syncthreads();
            if (tid == 0) {
                __builtin_amdgcn_fence(__ATOMIC_RELEASE, "agent");
                __hip_atomic_fetch_add(ctr, 1, __ATOMIC_RELAXED, __HIP_MEMORY_SCOPE_AGENT);
                const int tgt = 64 * (ss + 1);
                int spins = 0;
                while (__hip_atomic_load(ctr, __ATOMIC_RELAXED, __HIP_MEMORY_SCOPE_AGENT) < tgt) {
                    __builtin_amdgcn_s_sleep(2);
                    if (++spins > (1 << 18)) break;
                }
                __builtin_amdgcn_fence(__ATOMIC_ACQUIRE, "agent");
            }
            __syncthreads();
        }
    }
#undef LOADA
#undef LOADB
#undef MF
}

// ---------------- nz flags ----------------
__global__ __launch_bounds__(64) void nz_kernel(
    const float* __restrict__ he, int* __restrict__ nz)
{
    int rr = blockIdx.x;
    int lane = threadIdx.x;
    const float* row = he + (size_t)rr * HDIM;
    bool any = false;
    for (int k = lane; k < HDIM; k += 64) any |= (row[k] != 0.0f);
    unsigned long long b = __ballot(any);
    if (lane == 0) nz[rr] = (b != 0ull) ? 1 : 0;
}

// ---------------- text_rel expansion ----------------
__global__ __launch_bounds__(256) void expand_kernel(
    const float* __restrict__ he, const int* __restrict__ nz,
    float* __restrict__ out)
{
    int blk = blockIdx.x;               // ((b*10+i)*10+j)*10+k
    int k = blk % 10;
    int j = (blk / 10) % 10;
    int i = (blk / 100) % 10;
    int b = blk / 1000;
    int tid = threadIdx.x;
    float4* o = (float4*)(out + (size_t)blk * 1024);
    float4 z; z.x = z.y = z.z = z.w = 0.0f;
    if (tid < 128) {
        bool m = (j <= i) && (k <= i) && (nz[b*10 + k] != 0);
        float4 v = m ? ((const float4*)(he + (size_t)(b*10 + j) * HDIM))[tid] : z;
        o[tid] = v;
    } else {
        int c = tid - 128;
        bool m = (k <= i) && (j <= i) && (nz[b*10 + j] != 0);
        float4 v = m ? ((const float4*)(he + (size_t)(b*10 + k) * HDIM))[c] : z;
        o[128 + c] = v;
    }
}

extern "C" void kernel_launch(void* const* d_in, const int* in_sizes, int n_in,
                              void* d_out, int out_size, void* d_ws, size_t ws_size,
                              hipStream_t stream)
{
    (void)in_sizes; (void)n_in; (void)out_size; (void)ws_size;
    const int* ques     = (const int*)d_in[0];
    const int* hist     = (const int*)d_in[1];
    const int* ques_len = (const int*)d_in[2];
    const int* hist_len = (const int*)d_in[3];
    const float* w_emb  = (const float*)d_in[6];
    const float* elmo   = (const float*)d_in[7];
    const float* Wc     = (const float*)d_in[8];
    const float* bc     = (const float*)d_in[9];

    // ---- workspace layout ----
    char* ws = (char*)d_ws;
    size_t off = 0;
    auto alloc = [&](size_t bytes) { char* p = ws + off; off += (bytes + 255) & ~(size_t)255; return p; };
    ushort_t* XP0bf = (ushort_t*)alloc((size_t)19200 * G4 * 2);      // 78.6 MB
    ushort_t* Xb    = (ushort_t*)alloc((size_t)19200 * XPAD * 2);    // 32.0 MB
    ushort_t* Wcb   = (ushort_t*)alloc((size_t)HDIM * ELMOD * 2);
    ushort_t *Wih0b[2], *Whh0b[2], *Wcat[2];
    for (int s = 0; s < 2; ++s) {
        Wih0b[s] = (ushort_t*)alloc((size_t)G4 * XPAD * 2);
        Whh0b[s] = (ushort_t*)alloc((size_t)G4 * HDIM * 2);
        Wcat[s]  = (ushort_t*)alloc((size_t)G4 * ELMOD * 2);
    }
    char* state_base = ws + off;
    ushort_t* acat[2][2];
    for (int s = 0; s < 2; ++s)
        for (int p = 0; p < 2; ++p)
            acat[s][p] = (ushort_t*)alloc((size_t)NSEQ * ELMOD * 2);
    int* ctrs = (int*)alloc(256);
    size_t state_bytes = (ws + off) - state_base;
    float* he = (float*)alloc((size_t)NSEQ * HDIM * 4);
    int* nzb  = (int*)alloc(NSEQ * 4);

    float* out = (float*)d_out;
    float* ques_embed = out;
    float* text_rel   = out + (size_t)NSEQ * HDIM;

    const int rowoff[2] = {0, 6400};
    const int TT[2] = {20, 40};
    const int* lensp[2] = {ques_len, hist_len};

    // ---- all weight conversions: one launch ----
    ConvPack CP;
    {
        int ji = 0; long base = 0;
        auto addJob = [&](const float* src, ushort_t* dst, int sc, int ds, int doff, int fc, int rows) {
            CP.src[ji] = src; CP.dst[ji] = dst; CP.srcCols[ji] = sc; CP.dstStride[ji] = ds;
            CP.dstOff[ji] = doff; CP.fillCols[ji] = fc; CP.base[ji] = base;
            base += (long)fc * rows; ++ji;
        };
        addJob(Wc, Wcb, ELMOD, ELMOD, 0, ELMOD, HDIM);
        for (int s = 0; s < 2; ++s) {
            addJob((const float*)d_in[10 + 6*s], Wih0b[s], 812,  XPAD,  0,    XPAD, G4);
            addJob((const float*)d_in[11 + 6*s], Whh0b[s], HDIM, HDIM,  0,    HDIM, G4);
            addJob((const float*)d_in[13 + 6*s], Wcat[s],  HDIM, ELMOD, 0,    HDIM, G4);
            addJob((const float*)d_in[14 + 6*s], Wcat[s],  HDIM, ELMOD, HDIM, HDIM, G4);
        }
        CP.base[9] = base;
        int nblk = (int)((base + 255) / 256);
        conv_all_kernel<<<nblk, 256, 0, stream>>>(CP);
    }

    // ---- embeddings + input projections ----
    emb_gather_kernel<<<19200, 128, 0, stream>>>(ques, hist, w_emb, Xb);
    for (int s = 0; s < 2; ++s) {
        int Ntok = NSEQ * TT[s];
        ushort_t* XbS = Xb + (size_t)rowoff[s] * XPAD;
        const int* tok = s ? hist : ques;
        gemm_ff_kernel<<<dim3(HDIM/64, Ntok/64), 256, 0, stream>>>(
            nullptr, elmo, tok, ELMOD, Wcb, bc, XbS + EMBD, XPAD, ELMOD);
        const float* b0 = (const float*)d_in[12 + 6*s];
        gemm_ff_kernel<<<dim3(G4/64, Ntok/64), 256, 0, stream>>>(
            XbS, nullptr, nullptr, XPAD, Wih0b[s], b0,
            XP0bf + (size_t)rowoff[s] * G4, G4, XPAD);
    }

    // ---- zero recurrent state + barrier counters ----
    hipMemsetAsync(state_base, 0, state_bytes, stream);

    // ---- persistent LSTM: 128 blocks (4 cells x 32) ----
    PPack P;
    for (int s = 0; s < 2; ++s) {
        const float* b1 = (const float*)d_in[15 + 6*s];
        PCell& c0 = P.cell[s*2 + 0];
        c0.A0 = acat[s][0]; c0.A1 = acat[s][1];
        c0.B  = Whh0b[s];
        c0.xp = XP0bf + (size_t)rowoff[s] * G4;
        c0.bias = nullptr;
        c0.O0 = acat[s][0]; c0.O1 = acat[s][1];
        c0.hlast = nullptr; c0.lens = lensp[s];
        c0.K = HDIM; c0.T = TT[s]; c0.layer = 0;
        PCell& c1 = P.cell[s*2 + 1];
        c1.A0 = acat[s][0]; c1.A1 = acat[s][1];
        c1.B  = Wcat[s];
        c1.xp = nullptr; c1.bias = b1;
        c1.O0 = acat[s][0] + HDIM; c1.O1 = acat[s][1] + HDIM;
        c1.hlast = s ? he : ques_embed;
        c1.lens = lensp[s];
        c1.K = ELMOD; c1.T = TT[s]; c1.layer = 1;
    }
    lstm_persist_kernel<<<128, 256, 0, stream>>>(P, ctrs);

    // ---- expansion ----
    nz_kernel<<<NSEQ, 64, 0, stream>>>(he, nzb);
    expand_kernel<<<32000, 256, 0, stream>>>(he, nzb, text_rel);
}

// Round 5
// 1492.028 us; speedup vs baseline: 1.2706x; 1.0445x over previous
//
#include <hip/hip_runtime.h>
#include <math.h>

#define NSEQ 320
#define HDIM 512
#define G4   2048
#define EMBD 300
#define ELMOD 1024
#define XPAD 832          // 812 padded to multiple of 32

typedef __attribute__((ext_vector_type(8))) short bf16x8;
typedef __attribute__((ext_vector_type(4))) float f32x4;
typedef __attribute__((ext_vector_type(4))) unsigned int u32x4;
typedef unsigned short ushort_t;

__device__ __forceinline__ float sigmoidf_(float x) { return 1.0f / (1.0f + expf(-x)); }

__device__ __forceinline__ ushort_t f2bf(float f) {
    unsigned u = __float_as_uint(f);
    u = (u + 0x7FFFu + ((u >> 16) & 1u)) >> 16;   // RNE
    return (ushort_t)u;
}
__device__ __forceinline__ float bf2f(ushort_t u) {
    return __uint_as_float(((unsigned)u) << 16);
}
__device__ __forceinline__ unsigned pack2(float a, float b) {
    return (unsigned)f2bf(a) | ((unsigned)f2bf(b) << 16);
}

// ---------------- all weight conversions in ONE flat launch ----------------
struct ConvPack {
    const float* src[9];
    ushort_t* dst[9];
    int srcCols[9], dstStride[9], dstOff[9], fillCols[9];
    long base[10];
};

__global__ __launch_bounds__(256) void conv_all_kernel(ConvPack P)
{
    long gid = (long)blockIdx.x * 256 + threadIdx.x;
    if (gid >= P.base[9]) return;
    int job = 0;
    #pragma unroll
    for (int j = 1; j < 9; ++j) if (gid >= P.base[j]) job = j;
    int e  = (int)(gid - P.base[job]);
    int fc = P.fillCols[job];
    int r  = e / fc;
    int ci = e - r * fc;
    int sc = P.srcCols[job];
    float v = (ci < sc) ? P.src[job][(size_t)r * sc + ci] : 0.0f;
    P.dst[job][(size_t)r * P.dstStride[job] + P.dstOff[job] + ci] = f2bf(v);
}

// ---------------- GloVe gather (ques+hist merged) ----------------
__global__ __launch_bounds__(128) void emb_gather_kernel(
    const int* __restrict__ ques, const int* __restrict__ hist,
    const float* __restrict__ w_emb, ushort_t* __restrict__ Xb)
{
    int n = blockIdx.x;
    int tokid = (n < 6400) ? ques[n] : hist[n - 6400];
    int t = threadIdx.x;
    ushort_t* dst = Xb + (size_t)n * XPAD;
    if (t < 75) {
        const float4* src = (const float4*)(w_emb + (size_t)tokid * EMBD);
        float4 v = src[t];
        dst[4*t+0] = f2bf(v.x); dst[4*t+1] = f2bf(v.y);
        dst[4*t+2] = f2bf(v.z); dst[4*t+3] = f2bf(v.w);
    } else if (t >= 108) {  // 20 pad cols
        dst[812 + (t - 108)] = 0;
    }
}

// ---------------- feed-forward GEMM: C_bf16[M][N] = A[M][K] * W[N][K]^T + bias ----------------
__global__ __launch_bounds__(256) void gemm_ff_kernel(
    const ushort_t* __restrict__ Ab, const float* __restrict__ Af,
    const int* __restrict__ tok, int strideA,
    const ushort_t* __restrict__ W, const float* __restrict__ bias,
    ushort_t* __restrict__ C, int strideC, int K)
{
    __shared__ ushort_t As[64 * 40];
    __shared__ ushort_t Bs[64 * 40];
    const int m0 = blockIdx.y * 64;
    const int n0 = blockIdx.x * 64;
    const int tid = threadIdx.x;
    const int r  = tid >> 2;
    const int kq = (tid & 3) << 3;

    const ushort_t* arow_b = nullptr;
    const float*    arow_f = nullptr;
    if (Af) arow_f = Af + (size_t)tok[m0 + r] * strideA + kq;
    else    arow_b = Ab + (size_t)(m0 + r) * strideA + kq;
    const ushort_t* brow = W + (size_t)(n0 + r) * K + kq;

    const int lane = tid & 63;
    const int w = tid >> 6;
    const int wm = w & 1, wn = w >> 1;
    const int kc = (lane >> 4) << 3;

    f32x4 acc[2][2];
    #pragma unroll
    for (int f = 0; f < 2; ++f)
        #pragma unroll
        for (int g = 0; g < 2; ++g)
            acc[f][g] = (f32x4){0.f, 0.f, 0.f, 0.f};

    for (int k0 = 0; k0 < K; k0 += 32) {
        if (Af) {
            float4 v0 = ((const float4*)(arow_f + k0))[0];
            float4 v1 = ((const float4*)(arow_f + k0))[1];
            uint4 p; p.x = pack2(v0.x, v0.y); p.y = pack2(v0.z, v0.w);
            p.z = pack2(v1.x, v1.y); p.w = pack2(v1.z, v1.w);
            *(uint4*)&As[r*40 + kq] = p;
        } else {
            *(uint4*)&As[r*40 + kq] = *(const uint4*)(arow_b + k0);
        }
        *(uint4*)&Bs[r*40 + kq] = *(const uint4*)(brow + k0);
        __syncthreads();
        bf16x8 af[2], bfr[2];
        #pragma unroll
        for (int f = 0; f < 2; ++f)
            af[f] = *(const bf16x8*)&As[(wm*32 + f*16 + (lane & 15))*40 + kc];
        #pragma unroll
        for (int g = 0; g < 2; ++g)
            bfr[g] = *(const bf16x8*)&Bs[(wn*32 + g*16 + (lane & 15))*40 + kc];
        #pragma unroll
        for (int f = 0; f < 2; ++f)
            #pragma unroll
            for (int g = 0; g < 2; ++g)
                acc[f][g] = __builtin_amdgcn_mfma_f32_16x16x32_bf16(af[f], bfr[g], acc[f][g], 0, 0, 0);
        __syncthreads();
    }

    #pragma unroll
    for (int f = 0; f < 2; ++f) {
        #pragma unroll
        for (int g = 0; g < 2; ++g) {
            int col = n0 + wn*32 + g*16 + (lane & 15);
            float bv = bias[col];
            #pragma unroll
            for (int i = 0; i < 4; ++i) {
                int row = m0 + wm*32 + f*16 + ((lane >> 4) << 2) + i;
                C[(size_t)row * strideC + col] = f2bf(acc[f][g][i] + bv);
            }
        }
    }
}

// ---------------- persistent LSTM pieces ----------------
struct PCell {
    const ushort_t* A0; const ushort_t* A1;   // acat parity buffers (lda = 1024)
    const ushort_t* B;                        // [2048][K], row = gate*512 + j
    const ushort_t* xp;                       // L0: XP0 base (row n*T+t, stride 2048)
    const float* bias;                        // L1: b1
    ushort_t* O0; ushort_t* O1;               // h dest parity (stride 1024)
    float* hlast;                             // L1: fp32 dest when t == lens[n]-1
    const int* lens;
    int K, T, layer;
};
struct PPack { PCell cell[4]; };

// 3-deep hand-pipelined GEMM k-loop; A via system-scope (sc0 sc1) loads that
// bypass L1/L2 (coherent with producer's sc0 sc1 write-through stores -> no
// cache fences needed anywhere).
template<int NK>
__device__ __forceinline__ void gemm_kloop(
    const ushort_t* Ab, const int* aoff,
    const ushort_t* Bs, const int* bofs,
    f32x4 (&acc)[5][4])
{
    const ushort_t* ap[5];
    #pragma unroll
    for (int q = 0; q < 5; ++q) ap[q] = Ab + aoff[q];

    u32x4 b0[5], b1[5], b2[5];

#define AISS(BUF, KK) { _Pragma("unroll") for (int q = 0; q < 5; ++q) \
    asm volatile("global_load_dwordx4 %0, %1, off sc0 sc1" \
        : "=v"(BUF[q]) : "v"(ap[q] + (KK)*32)); }
#define MFBLK(BUF) { _Pragma("unroll") for (int q = 0; q < 5; ++q) { \
    _Pragma("unroll") for (int g = 0; g < 4; ++g) \
        acc[q][g] = __builtin_amdgcn_mfma_f32_16x16x32_bf16( \
            *(bf16x8*)&BUF[q], bfr[g], acc[q][g], 0, 0, 0); } }

    AISS(b0, 0); AISS(b1, 1); AISS(b2, 2);

    #pragma unroll
    for (int kk = 0; kk < NK; ++kk) {
        const int rem = NK - 1 - kk;
        if (rem >= 2)      asm volatile("s_waitcnt vmcnt(10)");
        else if (rem == 1) asm volatile("s_waitcnt vmcnt(5)");
        else               asm volatile("s_waitcnt vmcnt(0)");
        __builtin_amdgcn_sched_barrier(0);
        bf16x8 bfr[4];
        #pragma unroll
        for (int g = 0; g < 4; ++g)
            bfr[g] = *(const bf16x8*)&Bs[bofs[g] + kk*32];
        if (kk % 3 == 0)      { MFBLK(b0); if (kk + 3 < NK) AISS(b0, kk+3); }
        else if (kk % 3 == 1) { MFBLK(b1); if (kk + 3 < NK) AISS(b1, kk+3); }
        else                  { MFBLK(b2); if (kk + 3 < NK) AISS(b2, kk+3); }
    }
#undef AISS
#undef MFBLK
}

__global__ __launch_bounds__(256) void lstm_persist_kernel(PPack P, int* ctrs)
{
    // XCD-grouping swizzle (bijective; correctness doesn't depend on mapping)
    const int xcd    = blockIdx.x & 7;
    const int slot   = blockIdx.x >> 3;       // 0..15
    const int cellId = xcd >> 1;              // 0..3
    const int blk    = slot * 2 + (xcd & 1);  // 0..31
    const PCell c = P.cell[cellId];
    int* ctr = ctrs + (cellId >> 1) * 32;     // one counter per set

    const int tid  = threadIdx.x;
    const int w    = tid >> 6;
    const int lane = tid & 63;
    const int cc   = lane & 15;
    const int kg   = lane >> 4;
    const int j0   = blk * 16;
    const int K = c.K, T = c.T, PK = K + 8;

    __shared__ ushort_t Bs[64 * 1032];        // 129 KB (K=1024 padded)

    // ---- preload B slice (64 rows: gate = r>>4, jj = r&15) into LDS, once ----
    {
        const int CH = K >> 3;                // 16B chunks per row
        const int tot = 64 * CH;
        for (int idx = tid; idx < tot; idx += 256) {
            int r = idx / CH, ch = idx - r * CH;
            int gr = (r >> 4) * HDIM + j0 + (r & 15);
            *(u32x4*)&Bs[r * PK + ch * 8] = *(const u32x4*)(c.B + (size_t)gr * K + ch * 8);
        }
    }

    int aoff[5];
    #pragma unroll
    for (int q = 0; q < 5; ++q)
        aoff[q] = ((w*5 + q)*16 + cc) * 1024 + kg*8;
    int bofs[4];
    #pragma unroll
    for (int g = 0; g < 4; ++g)
        bofs[g] = (g*16 + cc) * PK + kg*8;

    float bias_r[4] = {0.f, 0.f, 0.f, 0.f};
    if (c.bias) {
        #pragma unroll
        for (int g = 0; g < 4; ++g) bias_r[g] = c.bias[g*HDIM + j0 + cc];
    }
    // packed lens (values <= 41 fit in a byte)
    unsigned lr[5];
    #pragma unroll
    for (int q = 0; q < 5; ++q) {
        unsigned pkd = 0;
        #pragma unroll
        for (int i = 0; i < 4; ++i)
            pkd |= ((unsigned)c.lens[(w*5+q)*16 + kg*4 + i] & 0xFF) << (8*i);
        lr[q] = pkd;
    }

    float creg[5][4];
    #pragma unroll
    for (int q = 0; q < 5; ++q)
        #pragma unroll
        for (int i = 0; i < 4; ++i) creg[q][i] = 0.f;

    __syncthreads();   // B preload visible to all waves

    for (int ss = 0; ss <= T; ++ss) {
        const int par = ss & 1;
        const bool active = c.layer ? (ss >= 1) : (ss < T);
        if (active) {
            const int t = c.layer ? (ss - 1) : ss;
            const ushort_t* Ab = par ? c.A1 : c.A0;
            ushort_t* Ob       = par ? c.O0 : c.O1;   // write parity par^1

            f32x4 acc[5][4];
            #pragma unroll
            for (int q = 0; q < 5; ++q)
                #pragma unroll
                for (int g = 0; g < 4; ++g)
                    acc[q][g] = (f32x4){0.f, 0.f, 0.f, 0.f};

            if (K == 512) gemm_kloop<16>(Ab, aoff, Bs, bofs, acc);
            else          gemm_kloop<32>(Ab, aoff, Bs, bofs, acc);
            __builtin_amdgcn_sched_barrier(0);

            #pragma unroll
            for (int q = 0; q < 5; ++q) {
                #pragma unroll
                for (int i = 0; i < 4; ++i) {
                    const int n = (w*5+q)*16 + kg*4 + i;
                    const int j = j0 + cc;
                    float gi = acc[q][0][i], gf = acc[q][1][i];
                    float gg = acc[q][2][i], go = acc[q][3][i];
                    if (c.xp) {
                        const ushort_t* xr = c.xp + ((size_t)n * T + t) * G4;
                        gi += bf2f(xr[j]);          gf += bf2f(xr[HDIM + j]);
                        gg += bf2f(xr[2*HDIM + j]); go += bf2f(xr[3*HDIM + j]);
                    } else {
                        gi += bias_r[0]; gf += bias_r[1];
                        gg += bias_r[2]; go += bias_r[3];
                    }
                    float cn = sigmoidf_(gf) * creg[q][i] + sigmoidf_(gi) * tanhf(gg);
                    creg[q][i] = cn;
                    float h = sigmoidf_(go) * tanhf(cn);
                    unsigned hb = (unsigned)f2bf(h);
                    unsigned pb = (unsigned)__shfl_xor((int)hb, 1);
                    if ((cc & 1) == 0) {
                        ushort_t* oaddr = Ob + (size_t)n * 1024 + j;
                        unsigned pv = hb | (pb << 16);
                        asm volatile("global_store_dword %0, %1, off sc0 sc1"
                                     :: "v"(oaddr), "v"(pv) : "memory");
                    }
                    if (c.hlast && t == (int)((lr[q] >> (8*i)) & 0xFF) - 1)
                        c.hlast[(size_t)n * HDIM + j] = h;
                }
            }
        }
        if (ss < T) {
            asm volatile("s_waitcnt vmcnt(0)" ::: "memory");
            __syncthreads();
            if (tid == 0) {
                __hip_atomic_fetch_add(ctr, 1, __ATOMIC_RELAXED, __HIP_MEMORY_SCOPE_AGENT);
                const int tgt = 64 * (ss + 1);
                int spins = 0;
                while (__hip_atomic_load(ctr, __ATOMIC_RELAXED, __HIP_MEMORY_SCOPE_AGENT) < tgt) {
                    __builtin_amdgcn_s_sleep(1);
                    if (++spins > (1 << 20)) break;
                }
            }
            __syncthreads();
        }
    }
}

// ---------------- nz flags ----------------
__global__ __launch_bounds__(64) void nz_kernel(
    const float* __restrict__ he, int* __restrict__ nz)
{
    int rr = blockIdx.x;
    int lane = threadIdx.x;
    const float* row = he + (size_t)rr * HDIM;
    bool any = false;
    for (int k = lane; k < HDIM; k += 64) any |= (row[k] != 0.0f);
    unsigned long long b = __ballot(any);
    if (lane == 0) nz[rr] = (b != 0ull) ? 1 : 0;
}

// ---------------- text_rel expansion ----------------
__global__ __launch_bounds__(256) void expand_kernel(
    const float* __restrict__ he, const int* __restrict__ nz,
    float* __restrict__ out)
{
    int blk = blockIdx.x;               // ((b*10+i)*10+j)*10+k
    int k = blk % 10;
    int j = (blk / 10) % 10;
    int i = (blk / 100) % 10;
    int b = blk / 1000;
    int tid = threadIdx.x;
    float4* o = (float4*)(out + (size_t)blk * 1024);
    float4 z; z.x = z.y = z.z = z.w = 0.0f;
    if (tid < 128) {
        bool m = (j <= i) && (k <= i) && (nz[b*10 + k] != 0);
        float4 v = m ? ((const float4*)(he + (size_t)(b*10 + j) * HDIM))[tid] : z;
        o[tid] = v;
    } else {
        int c = tid - 128;
        bool m = (k <= i) && (j <= i) && (nz[b*10 + j] != 0);
        float4 v = m ? ((const float4*)(he + (size_t)(b*10 + k) * HDIM))[c] : z;
        o[128 + c] = v;
    }
}

extern "C" void kernel_launch(void* const* d_in, const int* in_sizes, int n_in,
                              void* d_out, int out_size, void* d_ws, size_t ws_size,
                              hipStream_t stream)
{
    (void)in_sizes; (void)n_in; (void)out_size; (void)ws_size;
    const int* ques     = (const int*)d_in[0];
    const int* hist     = (const int*)d_in[1];
    const int* ques_len = (const int*)d_in[2];
    const int* hist_len = (const int*)d_in[3];
    const float* w_emb  = (const float*)d_in[6];
    const float* elmo   = (const float*)d_in[7];
    const float* Wc     = (const float*)d_in[8];
    const float* bc     = (const float*)d_in[9];

    // ---- workspace layout ----
    char* ws = (char*)d_ws;
    size_t off = 0;
    auto alloc = [&](size_t bytes) { char* p = ws + off; off += (bytes + 255) & ~(size_t)255; return p; };
    ushort_t* XP0bf = (ushort_t*)alloc((size_t)19200 * G4 * 2);      // 78.6 MB
    ushort_t* Xb    = (ushort_t*)alloc((size_t)19200 * XPAD * 2);    // 32.0 MB
    ushort_t* Wcb   = (ushort_t*)alloc((size_t)HDIM * ELMOD * 2);
    ushort_t *Wih0b[2], *Whh0b[2], *Wcat[2];
    for (int s = 0; s < 2; ++s) {
        Wih0b[s] = (ushort_t*)alloc((size_t)G4 * XPAD * 2);
        Whh0b[s] = (ushort_t*)alloc((size_t)G4 * HDIM * 2);
        Wcat[s]  = (ushort_t*)alloc((size_t)G4 * ELMOD * 2);
    }
    char* state_base = ws + off;
    ushort_t* acat[2][2];
    for (int s = 0; s < 2; ++s)
        for (int p = 0; p < 2; ++p)
            acat[s][p] = (ushort_t*)alloc((size_t)NSEQ * ELMOD * 2);
    int* ctrs = (int*)alloc(256);
    size_t state_bytes = (ws + off) - state_base;
    float* he = (float*)alloc((size_t)NSEQ * HDIM * 4);
    int* nzb  = (int*)alloc(NSEQ * 4);

    float* out = (float*)d_out;
    float* ques_embed = out;
    float* text_rel   = out + (size_t)NSEQ * HDIM;

    const int rowoff[2] = {0, 6400};
    const int TT[2] = {20, 40};
    const int* lensp[2] = {ques_len, hist_len};

    // ---- all weight conversions: one launch ----
    ConvPack CP;
    {
        int ji = 0; long base = 0;
        auto addJob = [&](const float* src, ushort_t* dst, int sc, int ds, int doff, int fc, int rows) {
            CP.src[ji] = src; CP.dst[ji] = dst; CP.srcCols[ji] = sc; CP.dstStride[ji] = ds;
            CP.dstOff[ji] = doff; CP.fillCols[ji] = fc; CP.base[ji] = base;
            base += (long)fc * rows; ++ji;
        };
        addJob(Wc, Wcb, ELMOD, ELMOD, 0, ELMOD, HDIM);
        for (int s = 0; s < 2; ++s) {
            addJob((const float*)d_in[10 + 6*s], Wih0b[s], 812,  XPAD,  0,    XPAD, G4);
            addJob((const float*)d_in[11 + 6*s], Whh0b[s], HDIM, HDIM,  0,    HDIM, G4);
            addJob((const float*)d_in[13 + 6*s], Wcat[s],  HDIM, ELMOD, 0,    HDIM, G4);
            addJob((const float*)d_in[14 + 6*s], Wcat[s],  HDIM, ELMOD, HDIM, HDIM, G4);
        }
        CP.base[9] = base;
        int nblk = (int)((base + 255) / 256);
        conv_all_kernel<<<nblk, 256, 0, stream>>>(CP);
    }

    // ---- embeddings + input projections ----
    emb_gather_kernel<<<19200, 128, 0, stream>>>(ques, hist, w_emb, Xb);
    for (int s = 0; s < 2; ++s) {
        int Ntok = NSEQ * TT[s];
        ushort_t* XbS = Xb + (size_t)rowoff[s] * XPAD;
        const int* tok = s ? hist : ques;
        gemm_ff_kernel<<<dim3(HDIM/64, Ntok/64), 256, 0, stream>>>(
            nullptr, elmo, tok, ELMOD, Wcb, bc, XbS + EMBD, XPAD, ELMOD);
        const float* b0 = (const float*)d_in[12 + 6*s];
        gemm_ff_kernel<<<dim3(G4/64, Ntok/64), 256, 0, stream>>>(
            XbS, nullptr, nullptr, XPAD, Wih0b[s], b0,
            XP0bf + (size_t)rowoff[s] * G4, G4, XPAD);
    }

    // ---- zero recurrent state + barrier counters (flushed at kernel end) ----
    hipMemsetAsync(state_base, 0, state_bytes, stream);

    // ---- persistent LSTM: 128 blocks (4 cells x 32) ----
    PPack P;
    for (int s = 0; s < 2; ++s) {
        const float* b1 = (const float*)d_in[15 + 6*s];
        PCell& c0 = P.cell[s*2 + 0];
        c0.A0 = acat[s][0]; c0.A1 = acat[s][1];
        c0.B  = Whh0b[s];
        c0.xp = XP0bf + (size_t)rowoff[s] * G4;
        c0.bias = nullptr;
        c0.O0 = acat[s][0]; c0.O1 = acat[s][1];
        c0.hlast = nullptr; c0.lens = lensp[s];
        c0.K = HDIM; c0.T = TT[s]; c0.layer = 0;
        PCell& c1 = P.cell[s*2 + 1];
        c1.A0 = acat[s][0]; c1.A1 = acat[s][1];
        c1.B  = Wcat[s];
        c1.xp = nullptr; c1.bias = b1;
        c1.O0 = acat[s][0] + HDIM; c1.O1 = acat[s][1] + HDIM;
        c1.hlast = s ? he : ques_embed;
        c1.lens = lensp[s];
        c1.K = ELMOD; c1.T = TT[s]; c1.layer = 1;
    }
    lstm_persist_kernel<<<128, 256, 0, stream>>>(P, ctrs);

    // ---- expansion ----
    nz_kernel<<<NSEQ, 64, 0, stream>>>(he, nzb);
    expand_kernel<<<32000, 256, 0, stream>>>(he, nzb, text_rel);
}

// Round 6
// 1458.576 us; speedup vs baseline: 1.2998x; 1.0229x over previous
//
#include <hip/hip_runtime.h>
#include <math.h>

#define NSEQ 320
#define HDIM 512
#define G4   2048
#define EMBD 300
#define ELMOD 1024
#define XPAD 832          // 812 padded to multiple of 32

typedef __attribute__((ext_vector_type(8))) short bf16x8;
typedef __attribute__((ext_vector_type(4))) float f32x4;
typedef __attribute__((ext_vector_type(4))) unsigned int u32x4;
typedef unsigned short ushort_t;

__device__ __forceinline__ float sigmoidf_(float x) { return 1.0f / (1.0f + expf(-x)); }

__device__ __forceinline__ ushort_t f2bf(float f) {
    unsigned u = __float_as_uint(f);
    u = (u + 0x7FFFu + ((u >> 16) & 1u)) >> 16;   // RNE
    return (ushort_t)u;
}
__device__ __forceinline__ float bf2f(ushort_t u) {
    return __uint_as_float(((unsigned)u) << 16);
}
__device__ __forceinline__ unsigned pack2(float a, float b) {
    return (unsigned)f2bf(a) | ((unsigned)f2bf(b) << 16);
}

// ---------------- all weight conversions in ONE flat launch ----------------
struct ConvPack {
    const float* src[9];
    ushort_t* dst[9];
    int srcCols[9], dstStride[9], dstOff[9], fillCols[9];
    long base[10];
};

__global__ __launch_bounds__(256) void conv_all_kernel(ConvPack P)
{
    long gid = (long)blockIdx.x * 256 + threadIdx.x;
    if (gid >= P.base[9]) return;
    int job = 0;
    #pragma unroll
    for (int j = 1; j < 9; ++j) if (gid >= P.base[j]) job = j;
    int e  = (int)(gid - P.base[job]);
    int fc = P.fillCols[job];
    int r  = e / fc;
    int ci = e - r * fc;
    int sc = P.srcCols[job];
    float v = (ci < sc) ? P.src[job][(size_t)r * sc + ci] : 0.0f;
    P.dst[job][(size_t)r * P.dstStride[job] + P.dstOff[job] + ci] = f2bf(v);
}

// ---------------- GloVe gather (ques+hist merged) ----------------
__global__ __launch_bounds__(128) void emb_gather_kernel(
    const int* __restrict__ ques, const int* __restrict__ hist,
    const float* __restrict__ w_emb, ushort_t* __restrict__ Xb)
{
    int n = blockIdx.x;
    int tokid = (n < 6400) ? ques[n] : hist[n - 6400];
    int t = threadIdx.x;
    ushort_t* dst = Xb + (size_t)n * XPAD;
    if (t < 75) {
        const float4* src = (const float4*)(w_emb + (size_t)tokid * EMBD);
        float4 v = src[t];
        dst[4*t+0] = f2bf(v.x); dst[4*t+1] = f2bf(v.y);
        dst[4*t+2] = f2bf(v.z); dst[4*t+3] = f2bf(v.w);
    } else if (t >= 108) {  // 20 pad cols
        dst[812 + (t - 108)] = 0;
    }
}

// ---------------- feed-forward GEMM: C_bf16[M][N] = A[M][K] * W[N][K]^T + bias ----------------
__global__ __launch_bounds__(256) void gemm_ff_kernel(
    const ushort_t* __restrict__ Ab, const float* __restrict__ Af,
    const int* __restrict__ tok, int strideA,
    const ushort_t* __restrict__ W, const float* __restrict__ bias,
    ushort_t* __restrict__ C, int strideC, int K)
{
    __shared__ ushort_t As[64 * 40];
    __shared__ ushort_t Bs[64 * 40];
    const int m0 = blockIdx.y * 64;
    const int n0 = blockIdx.x * 64;
    const int tid = threadIdx.x;
    const int r  = tid >> 2;
    const int kq = (tid & 3) << 3;

    const ushort_t* arow_b = nullptr;
    const float*    arow_f = nullptr;
    if (Af) arow_f = Af + (size_t)tok[m0 + r] * strideA + kq;
    else    arow_b = Ab + (size_t)(m0 + r) * strideA + kq;
    const ushort_t* brow = W + (size_t)(n0 + r) * K + kq;

    const int lane = tid & 63;
    const int w = tid >> 6;
    const int wm = w & 1, wn = w >> 1;
    const int kc = (lane >> 4) << 3;

    f32x4 acc[2][2];
    #pragma unroll
    for (int f = 0; f < 2; ++f)
        #pragma unroll
        for (int g = 0; g < 2; ++g)
            acc[f][g] = (f32x4){0.f, 0.f, 0.f, 0.f};

    for (int k0 = 0; k0 < K; k0 += 32) {
        if (Af) {
            float4 v0 = ((const float4*)(arow_f + k0))[0];
            float4 v1 = ((const float4*)(arow_f + k0))[1];
            uint4 p; p.x = pack2(v0.x, v0.y); p.y = pack2(v0.z, v0.w);
            p.z = pack2(v1.x, v1.y); p.w = pack2(v1.z, v1.w);
            *(uint4*)&As[r*40 + kq] = p;
        } else {
            *(uint4*)&As[r*40 + kq] = *(const uint4*)(arow_b + k0);
        }
        *(uint4*)&Bs[r*40 + kq] = *(const uint4*)(brow + k0);
        __syncthreads();
        bf16x8 af[2], bfr[2];
        #pragma unroll
        for (int f = 0; f < 2; ++f)
            af[f] = *(const bf16x8*)&As[(wm*32 + f*16 + (lane & 15))*40 + kc];
        #pragma unroll
        for (int g = 0; g < 2; ++g)
            bfr[g] = *(const bf16x8*)&Bs[(wn*32 + g*16 + (lane & 15))*40 + kc];
        #pragma unroll
        for (int f = 0; f < 2; ++f)
            #pragma unroll
            for (int g = 0; g < 2; ++g)
                acc[f][g] = __builtin_amdgcn_mfma_f32_16x16x32_bf16(af[f], bfr[g], acc[f][g], 0, 0, 0);
        __syncthreads();
    }

    #pragma unroll
    for (int f = 0; f < 2; ++f) {
        #pragma unroll
        for (int g = 0; g < 2; ++g) {
            int col = n0 + wn*32 + g*16 + (lane & 15);
            float bv = bias[col];
            #pragma unroll
            for (int i = 0; i < 4; ++i) {
                int row = m0 + wm*32 + f*16 + ((lane >> 4) << 2) + i;
                C[(size_t)row * strideC + col] = f2bf(acc[f][g][i] + bv);
            }
        }
    }
}

// ---------------- persistent LSTM pieces ----------------
struct PCell {
    const ushort_t* A0; const ushort_t* A1;   // acat parity buffers (lda = 1024)
    const ushort_t* B;                        // [2048][K], row = gate*512 + j
    const ushort_t* xp;                       // L0: XP0 base (row n*T+t, stride 2048)
    const float* bias;                        // L1: b1
    ushort_t* O0; ushort_t* O1;               // h dest parity (stride 1024)
    float* hlast;                             // L1: fp32 dest when t == lens[n]-1
    const int* lens;
    int K, T, layer;
};
struct PPack { PCell cell[4]; };

// Depth-4 LDS-staged k-loop. Wave w stages AND reads only rows [80w, 80w+80)
// of the A-chunk => no cross-wave dependency, no per-chunk barrier.
// Counted vmcnt keeps 3 chunks in flight (T3/T4 pattern). Race-free buffer
// reuse: lgkmcnt(0)+sched_barrier before MFMAs ensures chunk-c LDS reads
// completed before STAGE(c+4) rewrites buffer (c&3).
template<int NC>
__device__ __forceinline__ void gemm_step(
    const ushort_t* __restrict__ Ag, ushort_t* Ach, const ushort_t* Bs,
    int w, int lane, int PK, f32x4 (&acc)[5][2])
{
    const int cc  = lane & 15, kg = lane >> 4;
    const int r16 = lane >> 2, s16 = lane & 3;

#define STAGE(c) { _Pragma("unroll") for (int k = 0; k < 5; ++k) { \
    const ushort_t* gp = Ag + (size_t)(w*80 + k*16 + r16) * 1024 + (c)*32 + s16*8; \
    ushort_t* lp = &Ach[((c)&3)*10240 + (w*80 + k*16)*32]; \
    __builtin_amdgcn_global_load_lds((const __attribute__((address_space(1))) unsigned int*)gp, \
        (__attribute__((address_space(3))) unsigned int*)lp, 16, 0, 0); } }

    STAGE(0) STAGE(1) STAGE(2) STAGE(3)

    #pragma unroll
    for (int c = 0; c < NC; ++c) {
        const int infl = (NC - 1 - c) > 3 ? 3 : (NC - 1 - c);
        if (infl >= 3)      asm volatile("s_waitcnt vmcnt(15)" ::: "memory");
        else if (infl == 2) asm volatile("s_waitcnt vmcnt(10)" ::: "memory");
        else if (infl == 1) asm volatile("s_waitcnt vmcnt(5)"  ::: "memory");
        else                asm volatile("s_waitcnt vmcnt(0)"  ::: "memory");
        __builtin_amdgcn_sched_barrier(0);
        bf16x8 af[5], bfr[2];
        #pragma unroll
        for (int q = 0; q < 5; ++q)
            af[q] = *(const bf16x8*)&Ach[((c)&3)*10240 + ((w*5+q)*16 + cc)*32 + kg*8];
        #pragma unroll
        for (int nt = 0; nt < 2; ++nt)
            bfr[nt] = *(const bf16x8*)&Bs[(nt*16 + cc)*PK + c*32 + kg*8];
        asm volatile("s_waitcnt lgkmcnt(0)" ::: "memory");
        __builtin_amdgcn_sched_barrier(0);
        #pragma unroll
        for (int q = 0; q < 5; ++q) {
            acc[q][0] = __builtin_amdgcn_mfma_f32_16x16x32_bf16(af[q], bfr[0], acc[q][0], 0, 0, 0);
            acc[q][1] = __builtin_amdgcn_mfma_f32_16x16x32_bf16(af[q], bfr[1], acc[q][1], 0, 0, 0);
        }
        __builtin_amdgcn_sched_barrier(0);
        if (c + 4 < NC) STAGE(c + 4)
    }
#undef STAGE
}

__global__ __launch_bounds__(256) void lstm_persist_kernel(PPack P, int* ctrs)
{
    const int cellId = blockIdx.x & 3;        // interleave cells across XCDs
    const int blk    = blockIdx.x >> 2;       // 0..63
    const PCell cl = P.cell[cellId];
    int* ctr = ctrs + (cellId >> 1) * 32;     // one counter per set (128 blocks each)

    const int tid  = threadIdx.x;
    const int w    = tid >> 6;
    const int lane = tid & 63;
    const int cc   = lane & 15;
    const int kg   = lane >> 4;
    const int half = cc >> 3;
    const int j0   = blk * 8;
    const int K = cl.K, T = cl.T, PK = K + 8;

    __shared__ ushort_t Bs[32 * 1032];        // 66.0 KB (K=1024 padded)
    __shared__ ushort_t Ach[4 * 10240];       // 81.9 KB: 4 chunk bufs x 320 rows x 32 cols

    // ---- preload B slice (32 rows: gate = r>>3, jj = r&7) into LDS, once ----
    {
        const int CH = K >> 3;
        const int tot = 32 * CH;
        for (int idx = tid; idx < tot; idx += 256) {
            int r = idx / CH, ch = idx - r * CH;
            int gr = (r >> 3) * HDIM + j0 + (r & 7);
            *(u32x4*)&Bs[r * PK + ch * 8] = *(const u32x4*)(cl.B + (size_t)gr * K + ch * 8);
        }
    }

    const int j = j0 + (cc & 7);
    float bmy0 = 0.f, bmy1 = 0.f;
    if (cl.bias) {
        bmy0 = cl.bias[half * HDIM + j];
        bmy1 = cl.bias[(2 + half) * HDIM + j];
    }
    // packed lens (values <= 41 fit in a byte)
    unsigned lr[5];
    #pragma unroll
    for (int q = 0; q < 5; ++q) {
        unsigned pkd = 0;
        #pragma unroll
        for (int i = 0; i < 4; ++i)
            pkd |= ((unsigned)cl.lens[(w*5+q)*16 + kg*4 + i] & 0xFF) << (8*i);
        lr[q] = pkd;
    }

    float creg[5][4];
    #pragma unroll
    for (int q = 0; q < 5; ++q)
        #pragma unroll
        for (int i = 0; i < 4; ++i) creg[q][i] = 0.f;

    __syncthreads();   // B preload visible to all waves

    for (int ss = 0; ss <= T; ++ss) {
        const int par = ss & 1;
        const bool active = cl.layer ? (ss >= 1) : (ss < T);
        if (active) {
            const int t = cl.layer ? (ss - 1) : ss;
            const ushort_t* Ab = par ? cl.A1 : cl.A0;
            ushort_t* Ob       = par ? cl.O0 : cl.O1;   // write parity par^1

            f32x4 acc[5][2];
            #pragma unroll
            for (int q = 0; q < 5; ++q) {
                acc[q][0] = (f32x4){0.f, 0.f, 0.f, 0.f};
                acc[q][1] = (f32x4){0.f, 0.f, 0.f, 0.f};
            }

            if (K == 512) gemm_step<16>(Ab, Ach, Bs, w, lane, PK, acc);
            else          gemm_step<32>(Ab, Ach, Bs, w, lane, PK, acc);
            __builtin_amdgcn_sched_barrier(0);

            #pragma unroll
            for (int q = 0; q < 5; ++q) {
                #pragma unroll
                for (int i = 0; i < 4; ++i) {
                    const int n = (w*5+q)*16 + kg*4 + i;
                    float v0 = acc[q][0][i];   // gate half      (i or f)
                    float v1 = acc[q][1][i];   // gate 2+half    (g or o)
                    if (cl.xp) {
                        const ushort_t* xr = cl.xp + ((size_t)n * T + t) * G4;
                        v0 += bf2f(xr[half * HDIM + j]);
                        v1 += bf2f(xr[(2 + half) * HDIM + j]);
                    } else {
                        v0 += bmy0; v1 += bmy1;
                    }
                    float p0 = __shfl_xor(v0, 8);
                    float p1 = __shfl_xor(v1, 8);
                    float gi = half ? p0 : v0;
                    float gf = half ? v0 : p0;
                    float gg = half ? p1 : v1;
                    float go = half ? v1 : p1;
                    float cn = sigmoidf_(gf) * creg[q][i] + sigmoidf_(gi) * tanhf(gg);
                    creg[q][i] = cn;
                    float h = sigmoidf_(go) * tanhf(cn);
                    unsigned hb = (unsigned)f2bf(h);
                    unsigned pb = (unsigned)__shfl_xor((int)hb, 1);
                    if (half == 0 && (cc & 1) == 0) {
                        ushort_t* oaddr = Ob + (size_t)n * 1024 + j;
                        unsigned pv = hb | (pb << 16);
                        asm volatile("global_store_dword %0, %1, off sc0 sc1"
                                     :: "v"(oaddr), "v"(pv) : "memory");
                    }
                    if (cl.hlast && half == 0 && t == (int)((lr[q] >> (8*i)) & 0xFF) - 1)
                        cl.hlast[(size_t)n * HDIM + j] = h;
                }
            }
        }
        if (ss < T) {
            asm volatile("s_waitcnt vmcnt(0)" ::: "memory");
            __syncthreads();
            if (tid == 0) {
                __hip_atomic_fetch_add(ctr, 1, __ATOMIC_RELAXED, __HIP_MEMORY_SCOPE_AGENT);
                const int tgt = 128 * (ss + 1);
                int spins = 0;
                while (__hip_atomic_load(ctr, __ATOMIC_RELAXED, __HIP_MEMORY_SCOPE_AGENT) < tgt) {
                    __builtin_amdgcn_s_sleep(1);
                    if (++spins > (1 << 20)) break;
                }
                // acquire: invalidate L1+L2 so cached A-loads see fresh h
                __builtin_amdgcn_fence(__ATOMIC_ACQUIRE, "agent");
            }
            __syncthreads();
        }
    }
}

// ---------------- nz flags ----------------
__global__ __launch_bounds__(64) void nz_kernel(
    const float* __restrict__ he, int* __restrict__ nz)
{
    int rr = blockIdx.x;
    int lane = threadIdx.x;
    const float* row = he + (size_t)rr * HDIM;
    bool any = false;
    for (int k = lane; k < HDIM; k += 64) any |= (row[k] != 0.0f);
    unsigned long long b = __ballot(any);
    if (lane == 0) nz[rr] = (b != 0ull) ? 1 : 0;
}

// ---------------- text_rel expansion ----------------
__global__ __launch_bounds__(256) void expand_kernel(
    const float* __restrict__ he, const int* __restrict__ nz,
    float* __restrict__ out)
{
    int blk = blockIdx.x;               // ((b*10+i)*10+j)*10+k
    int k = blk % 10;
    int j = (blk / 10) % 10;
    int i = (blk / 100) % 10;
    int b = blk / 1000;
    int tid = threadIdx.x;
    float4* o = (float4*)(out + (size_t)blk * 1024);
    float4 z; z.x = z.y = z.z = z.w = 0.0f;
    if (tid < 128) {
        bool m = (j <= i) && (k <= i) && (nz[b*10 + k] != 0);
        float4 v = m ? ((const float4*)(he + (size_t)(b*10 + j) * HDIM))[tid] : z;
        o[tid] = v;
    } else {
        int c = tid - 128;
        bool m = (k <= i) && (j <= i) && (nz[b*10 + j] != 0);
        float4 v = m ? ((const float4*)(he + (size_t)(b*10 + k) * HDIM))[c] : z;
        o[128 + c] = v;
    }
}

extern "C" void kernel_launch(void* const* d_in, const int* in_sizes, int n_in,
                              void* d_out, int out_size, void* d_ws, size_t ws_size,
                              hipStream_t stream)
{
    (void)in_sizes; (void)n_in; (void)out_size; (void)ws_size;
    const int* ques     = (const int*)d_in[0];
    const int* hist     = (const int*)d_in[1];
    const int* ques_len = (const int*)d_in[2];
    const int* hist_len = (const int*)d_in[3];
    const float* w_emb  = (const float*)d_in[6];
    const float* elmo   = (const float*)d_in[7];
    const float* Wc     = (const float*)d_in[8];
    const float* bc     = (const float*)d_in[9];

    // ---- workspace layout ----
    char* ws = (char*)d_ws;
    size_t off = 0;
    auto alloc = [&](size_t bytes) { char* p = ws + off; off += (bytes + 255) & ~(size_t)255; return p; };
    ushort_t* XP0bf = (ushort_t*)alloc((size_t)19200 * G4 * 2);      // 78.6 MB
    ushort_t* Xb    = (ushort_t*)alloc((size_t)19200 * XPAD * 2);    // 32.0 MB
    ushort_t* Wcb   = (ushort_t*)alloc((size_t)HDIM * ELMOD * 2);
    ushort_t *Wih0b[2], *Whh0b[2], *Wcat[2];
    for (int s = 0; s < 2; ++s) {
        Wih0b[s] = (ushort_t*)alloc((size_t)G4 * XPAD * 2);
        Whh0b[s] = (ushort_t*)alloc((size_t)G4 * HDIM * 2);
        Wcat[s]  = (ushort_t*)alloc((size_t)G4 * ELMOD * 2);
    }
    char* state_base = ws + off;
    ushort_t* acat[2][2];
    for (int s = 0; s < 2; ++s)
        for (int p = 0; p < 2; ++p)
            acat[s][p] = (ushort_t*)alloc((size_t)NSEQ * ELMOD * 2);
    int* ctrs = (int*)alloc(256);
    size_t state_bytes = (ws + off) - state_base;
    float* he = (float*)alloc((size_t)NSEQ * HDIM * 4);
    int* nzb  = (int*)alloc(NSEQ * 4);

    float* out = (float*)d_out;
    float* ques_embed = out;
    float* text_rel   = out + (size_t)NSEQ * HDIM;

    const int rowoff[2] = {0, 6400};
    const int TT[2] = {20, 40};
    const int* lensp[2] = {ques_len, hist_len};

    // ---- all weight conversions: one launch ----
    ConvPack CP;
    {
        int ji = 0; long base = 0;
        auto addJob = [&](const float* src, ushort_t* dst, int sc, int ds, int doff, int fc, int rows) {
            CP.src[ji] = src; CP.dst[ji] = dst; CP.srcCols[ji] = sc; CP.dstStride[ji] = ds;
            CP.dstOff[ji] = doff; CP.fillCols[ji] = fc; CP.base[ji] = base;
            base += (long)fc * rows; ++ji;
        };
        addJob(Wc, Wcb, ELMOD, ELMOD, 0, ELMOD, HDIM);
        for (int s = 0; s < 2; ++s) {
            addJob((const float*)d_in[10 + 6*s], Wih0b[s], 812,  XPAD,  0,    XPAD, G4);
            addJob((const float*)d_in[11 + 6*s], Whh0b[s], HDIM, HDIM,  0,    HDIM, G4);
            addJob((const float*)d_in[13 + 6*s], Wcat[s],  HDIM, ELMOD, 0,    HDIM, G4);
            addJob((const float*)d_in[14 + 6*s], Wcat[s],  HDIM, ELMOD, HDIM, HDIM, G4);
        }
        CP.base[9] = base;
        int nblk = (int)((base + 255) / 256);
        conv_all_kernel<<<nblk, 256, 0, stream>>>(CP);
    }

    // ---- embeddings + input projections ----
    emb_gather_kernel<<<19200, 128, 0, stream>>>(ques, hist, w_emb, Xb);
    for (int s = 0; s < 2; ++s) {
        int Ntok = NSEQ * TT[s];
        ushort_t* XbS = Xb + (size_t)rowoff[s] * XPAD;
        const int* tok = s ? hist : ques;
        gemm_ff_kernel<<<dim3(HDIM/64, Ntok/64), 256, 0, stream>>>(
            nullptr, elmo, tok, ELMOD, Wcb, bc, XbS + EMBD, XPAD, ELMOD);
        const float* b0 = (const float*)d_in[12 + 6*s];
        gemm_ff_kernel<<<dim3(G4/64, Ntok/64), 256, 0, stream>>>(
            XbS, nullptr, nullptr, XPAD, Wih0b[s], b0,
            XP0bf + (size_t)rowoff[s] * G4, G4, XPAD);
    }

    // ---- zero recurrent state + barrier counters ----
    hipMemsetAsync(state_base, 0, state_bytes, stream);

    // ---- persistent LSTM: 256 blocks (4 cells x 64, interleaved) ----
    PPack P;
    for (int s = 0; s < 2; ++s) {
        const float* b1 = (const float*)d_in[15 + 6*s];
        PCell& c0 = P.cell[s*2 + 0];
        c0.A0 = acat[s][0]; c0.A1 = acat[s][1];
        c0.B  = Whh0b[s];
        c0.xp = XP0bf + (size_t)rowoff[s] * G4;
        c0.bias = nullptr;
        c0.O0 = acat[s][0]; c0.O1 = acat[s][1];
        c0.hlast = nullptr; c0.lens = lensp[s];
        c0.K = HDIM; c0.T = TT[s]; c0.layer = 0;
        PCell& c1 = P.cell[s*2 + 1];
        c1.A0 = acat[s][0]; c1.A1 = acat[s][1];
        c1.B  = Wcat[s];
        c1.xp = nullptr; c1.bias = b1;
        c1.O0 = acat[s][0] + HDIM; c1.O1 = acat[s][1] + HDIM;
        c1.hlast = s ? he : ques_embed;
        c1.lens = lensp[s];
        c1.K = ELMOD; c1.T = TT[s]; c1.layer = 1;
    }
    lstm_persist_kernel<<<256, 256, 0, stream>>>(P, ctrs);

    // ---- expansion ----
    nz_kernel<<<NSEQ, 64, 0, stream>>>(he, nzb);
    expand_kernel<<<32000, 256, 0, stream>>>(he, nzb, text_rel);
}

// Round 7
// 1269.560 us; speedup vs baseline: 1.4933x; 1.1489x over previous
//
#include <hip/hip_runtime.h>
#include <math.h>

#define NSEQ 320
#define HDIM 512
#define G4   2048
#define EMBD 300
#define ELMOD 1024
#define XPAD 832          // 812 padded to multiple of 32

typedef __attribute__((ext_vector_type(8))) short bf16x8;
typedef __attribute__((ext_vector_type(4))) float f32x4;
typedef __attribute__((ext_vector_type(4))) unsigned int u32x4;
typedef unsigned short ushort_t;

__device__ __forceinline__ float sigmoidf_(float x) { return 1.0f / (1.0f + expf(-x)); }

__device__ __forceinline__ ushort_t f2bf(float f) {
    unsigned u = __float_as_uint(f);
    u = (u + 0x7FFFu + ((u >> 16) & 1u)) >> 16;   // RNE
    return (ushort_t)u;
}
__device__ __forceinline__ float bf2f(ushort_t u) {
    return __uint_as_float(((unsigned)u) << 16);
}
__device__ __forceinline__ unsigned pack2(float a, float b) {
    return (unsigned)f2bf(a) | ((unsigned)f2bf(b) << 16);
}

// ---------------- all weight conversions in ONE flat launch ----------------
struct ConvPack {
    const float* src[9];
    ushort_t* dst[9];
    int srcCols[9], dstStride[9], dstOff[9], fillCols[9];
    long base[10];
};

__global__ __launch_bounds__(256) void conv_all_kernel(ConvPack P)
{
    long gid = (long)blockIdx.x * 256 + threadIdx.x;
    if (gid >= P.base[9]) return;
    int job = 0;
    #pragma unroll
    for (int j = 1; j < 9; ++j) if (gid >= P.base[j]) job = j;
    int e  = (int)(gid - P.base[job]);
    int fc = P.fillCols[job];
    int r  = e / fc;
    int ci = e - r * fc;
    int sc = P.srcCols[job];
    float v = (ci < sc) ? P.src[job][(size_t)r * sc + ci] : 0.0f;
    P.dst[job][(size_t)r * P.dstStride[job] + P.dstOff[job] + ci] = f2bf(v);
}

// ---------------- GloVe gather (ques+hist merged) ----------------
__global__ __launch_bounds__(128) void emb_gather_kernel(
    const int* __restrict__ ques, const int* __restrict__ hist,
    const float* __restrict__ w_emb, ushort_t* __restrict__ Xb)
{
    int n = blockIdx.x;
    int tokid = (n < 6400) ? ques[n] : hist[n - 6400];
    int t = threadIdx.x;
    ushort_t* dst = Xb + (size_t)n * XPAD;
    if (t < 75) {
        const float4* src = (const float4*)(w_emb + (size_t)tokid * EMBD);
        float4 v = src[t];
        dst[4*t+0] = f2bf(v.x); dst[4*t+1] = f2bf(v.y);
        dst[4*t+2] = f2bf(v.z); dst[4*t+3] = f2bf(v.w);
    } else if (t >= 108) {  // 20 pad cols
        dst[812 + (t - 108)] = 0;
    }
}

// ---------------- feed-forward GEMM: C_bf16[M][N] = A[M][K] * W[N][K]^T + bias ----------------
__global__ __launch_bounds__(256) void gemm_ff_kernel(
    const ushort_t* __restrict__ Ab, const float* __restrict__ Af,
    const int* __restrict__ tok, int strideA,
    const ushort_t* __restrict__ W, const float* __restrict__ bias,
    ushort_t* __restrict__ C, int strideC, int K)
{
    __shared__ ushort_t As[64 * 40];
    __shared__ ushort_t Bs[64 * 40];
    const int m0 = blockIdx.y * 64;
    const int n0 = blockIdx.x * 64;
    const int tid = threadIdx.x;
    const int r  = tid >> 2;
    const int kq = (tid & 3) << 3;

    const ushort_t* arow_b = nullptr;
    const float*    arow_f = nullptr;
    if (Af) arow_f = Af + (size_t)tok[m0 + r] * strideA + kq;
    else    arow_b = Ab + (size_t)(m0 + r) * strideA + kq;
    const ushort_t* brow = W + (size_t)(n0 + r) * K + kq;

    const int lane = tid & 63;
    const int w = tid >> 6;
    const int wm = w & 1, wn = w >> 1;
    const int kc = (lane >> 4) << 3;

    f32x4 acc[2][2];
    #pragma unroll
    for (int f = 0; f < 2; ++f)
        #pragma unroll
        for (int g = 0; g < 2; ++g)
            acc[f][g] = (f32x4){0.f, 0.f, 0.f, 0.f};

    for (int k0 = 0; k0 < K; k0 += 32) {
        if (Af) {
            float4 v0 = ((const float4*)(arow_f + k0))[0];
            float4 v1 = ((const float4*)(arow_f + k0))[1];
            uint4 p; p.x = pack2(v0.x, v0.y); p.y = pack2(v0.z, v0.w);
            p.z = pack2(v1.x, v1.y); p.w = pack2(v1.z, v1.w);
            *(uint4*)&As[r*40 + kq] = p;
        } else {
            *(uint4*)&As[r*40 + kq] = *(const uint4*)(arow_b + k0);
        }
        *(uint4*)&Bs[r*40 + kq] = *(const uint4*)(brow + k0);
        __syncthreads();
        bf16x8 af[2], bfr[2];
        #pragma unroll
        for (int f = 0; f < 2; ++f)
            af[f] = *(const bf16x8*)&As[(wm*32 + f*16 + (lane & 15))*40 + kc];
        #pragma unroll
        for (int g = 0; g < 2; ++g)
            bfr[g] = *(const bf16x8*)&Bs[(wn*32 + g*16 + (lane & 15))*40 + kc];
        #pragma unroll
        for (int f = 0; f < 2; ++f)
            #pragma unroll
            for (int g = 0; g < 2; ++g)
                acc[f][g] = __builtin_amdgcn_mfma_f32_16x16x32_bf16(af[f], bfr[g], acc[f][g], 0, 0, 0);
        __syncthreads();
    }

    #pragma unroll
    for (int f = 0; f < 2; ++f) {
        #pragma unroll
        for (int g = 0; g < 2; ++g) {
            int col = n0 + wn*32 + g*16 + (lane & 15);
            float bv = bias[col];
            #pragma unroll
            for (int i = 0; i < 4; ++i) {
                int row = m0 + wm*32 + f*16 + ((lane >> 4) << 2) + i;
                C[(size_t)row * strideC + col] = f2bf(acc[f][g][i] + bv);
            }
        }
    }
}

// ---------------- persistent LSTM pieces ----------------
struct PCell {
    const ushort_t* A0; const ushort_t* A1;   // acat parity buffers (lda = 1024)
    const ushort_t* B;                        // [2048][K], row = gate*512 + j
    const ushort_t* xp;                       // L0: XP0 base (row n*T+t, stride 2048)
    const float* bias;                        // L1: b1
    ushort_t* O0; ushort_t* O1;               // h dest parity (stride 1024)
    float* hlast;                             // L1: fp32 dest when t == lens[n]-1
    const int* lens;
    int K, T, layer;
};
struct PPack { PCell cell[4]; };

// Depth-4 LDS-staged k-loop. Wave w stages AND reads only rows [80w, 80w+80)
// of the A-chunk => no cross-wave dependency, no per-chunk barrier.
// Counted vmcnt keeps 3 chunks in flight. Race-free buffer reuse:
// lgkmcnt(0)+sched_barrier before STAGE(c+4) ensures chunk-c LDS reads
// completed before buffer (c&3) is rewritten. STAGE is issued BEFORE the
// MFMA cluster so loads get ~250cy more flight time.
template<int NC>
__device__ __forceinline__ void gemm_step(
    const ushort_t* __restrict__ Ag, ushort_t* Ach, const ushort_t* Bs,
    int w, int lane, int PK, f32x4 (&acc)[5][2])
{
    const int cc  = lane & 15, kg = lane >> 4;
    const int r16 = lane >> 2, s16 = lane & 3;

#define STAGE(c) { _Pragma("unroll") for (int k = 0; k < 5; ++k) { \
    const ushort_t* gp = Ag + (size_t)(w*80 + k*16 + r16) * 1024 + (c)*32 + s16*8; \
    ushort_t* lp = &Ach[((c)&3)*10240 + (w*80 + k*16)*32]; \
    __builtin_amdgcn_global_load_lds((const __attribute__((address_space(1))) unsigned int*)gp, \
        (__attribute__((address_space(3))) unsigned int*)lp, 16, 0, 0); } }

    STAGE(0) STAGE(1) STAGE(2) STAGE(3)

    #pragma unroll
    for (int c = 0; c < NC; ++c) {
        const int infl = (NC - 1 - c) > 3 ? 3 : (NC - 1 - c);
        if (infl >= 3)      asm volatile("s_waitcnt vmcnt(15)" ::: "memory");
        else if (infl == 2) asm volatile("s_waitcnt vmcnt(10)" ::: "memory");
        else if (infl == 1) asm volatile("s_waitcnt vmcnt(5)"  ::: "memory");
        else                asm volatile("s_waitcnt vmcnt(0)"  ::: "memory");
        __builtin_amdgcn_sched_barrier(0);
        bf16x8 af[5], bfr[2];
        #pragma unroll
        for (int q = 0; q < 5; ++q)
            af[q] = *(const bf16x8*)&Ach[((c)&3)*10240 + ((w*5+q)*16 + cc)*32 + kg*8];
        #pragma unroll
        for (int nt = 0; nt < 2; ++nt)
            bfr[nt] = *(const bf16x8*)&Bs[(nt*16 + cc)*PK + c*32 + kg*8];
        asm volatile("s_waitcnt lgkmcnt(0)" ::: "memory");
        __builtin_amdgcn_sched_barrier(0);
        if (c + 4 < NC) STAGE(c + 4)
        #pragma unroll
        for (int q = 0; q < 5; ++q) {
            acc[q][0] = __builtin_amdgcn_mfma_f32_16x16x32_bf16(af[q], bfr[0], acc[q][0], 0, 0, 0);
            acc[q][1] = __builtin_amdgcn_mfma_f32_16x16x32_bf16(af[q], bfr[1], acc[q][1], 0, 0, 0);
        }
        __builtin_amdgcn_sched_barrier(0);
    }
#undef STAGE
}

__global__ __launch_bounds__(256) void lstm_persist_kernel(PPack P, int* ctrs)
{
    const int cellId = blockIdx.x & 3;        // interleave cells across XCDs
    const int blk    = blockIdx.x >> 2;       // 0..63
    const PCell cl = P.cell[cellId];
    int* ctr = ctrs + (cellId >> 1) * 32;     // one counter per set (128 blocks each)

    const int tid  = threadIdx.x;
    const int w    = tid >> 6;
    const int lane = tid & 63;
    const int cc   = lane & 15;
    const int kg   = lane >> 4;
    const int half = cc >> 3;
    const int j0   = blk * 8;
    const int K = cl.K, T = cl.T, PK = K + 16;   // stride%64==16 -> 4-way banks

    __shared__ ushort_t Bs[32 * 1040];        // 66.6 KB (K=1024 padded)
    __shared__ ushort_t Ach[4 * 10240];       // 81.9 KB: 4 chunk bufs x 320 rows x 32 cols

    // ---- preload B slice (32 rows: gate = r>>3, jj = r&7) into LDS, once ----
    {
        const int CH = K >> 3;
        const int tot = 32 * CH;
        for (int idx = tid; idx < tot; idx += 256) {
            int r = idx / CH, ch = idx - r * CH;
            int gr = (r >> 3) * HDIM + j0 + (r & 7);
            *(u32x4*)&Bs[r * PK + ch * 8] = *(const u32x4*)(cl.B + (size_t)gr * K + ch * 8);
        }
    }

    const int j = j0 + (cc & 7);
    float bmy0 = 0.f, bmy1 = 0.f;
    if (cl.bias) {
        bmy0 = cl.bias[half * HDIM + j];
        bmy1 = cl.bias[(2 + half) * HDIM + j];
    }
    // packed lens (values <= 41 fit in a byte)
    unsigned lr[5];
    #pragma unroll
    for (int q = 0; q < 5; ++q) {
        unsigned pkd = 0;
        #pragma unroll
        for (int i = 0; i < 4; ++i)
            pkd |= ((unsigned)cl.lens[(w*5+q)*16 + kg*4 + i] & 0xFF) << (8*i);
        lr[q] = pkd;
    }

    float creg[5][4];
    #pragma unroll
    for (int q = 0; q < 5; ++q)
        #pragma unroll
        for (int i = 0; i < 4; ++i) creg[q][i] = 0.f;

    __syncthreads();   // B preload visible to all waves

    for (int ss = 0; ss <= T; ++ss) {
        const int par = ss & 1;
        const bool active = cl.layer ? (ss >= 1) : (ss < T);
        if (active) {
            const int t = cl.layer ? (ss - 1) : ss;
            const ushort_t* Ab = par ? cl.A1 : cl.A0;
            ushort_t* Ob       = par ? cl.O0 : cl.O1;   // write parity par^1

            // ---- prefetch ALL xp gate-addends BEFORE the GEMM (L0 cells) ----
            // 40 scalar bf16 loads packed into 20 uints; the k-loop's ~8us of
            // MFMA+staging hides their HBM latency. Pinned before the k-loop
            // by the vmcnt asm "memory" clobbers inside gemm_step.
            unsigned xpk[5][4];
            if (cl.xp) {
                #pragma unroll
                for (int q = 0; q < 5; ++q) {
                    #pragma unroll
                    for (int i = 0; i < 4; ++i) {
                        const int n = (w*5+q)*16 + kg*4 + i;
                        const ushort_t* xr = cl.xp + ((size_t)n * T + t) * G4;
                        unsigned lo = xr[half * HDIM + j];
                        unsigned hi = xr[(2 + half) * HDIM + j];
                        xpk[q][i] = lo | (hi << 16);
                    }
                }
            }

            f32x4 acc[5][2];
            #pragma unroll
            for (int q = 0; q < 5; ++q) {
                acc[q][0] = (f32x4){0.f, 0.f, 0.f, 0.f};
                acc[q][1] = (f32x4){0.f, 0.f, 0.f, 0.f};
            }

            if (K == 512) gemm_step<16>(Ab, Ach, Bs, w, lane, PK, acc);
            else          gemm_step<32>(Ab, Ach, Bs, w, lane, PK, acc);
            __builtin_amdgcn_sched_barrier(0);

            #pragma unroll
            for (int q = 0; q < 5; ++q) {
                #pragma unroll
                for (int i = 0; i < 4; ++i) {
                    const int n = (w*5+q)*16 + kg*4 + i;
                    float v0 = acc[q][0][i];   // gate half      (i or f)
                    float v1 = acc[q][1][i];   // gate 2+half    (g or o)
                    if (cl.xp) {
                        v0 += __uint_as_float(xpk[q][i] << 16);
                        v1 += __uint_as_float(xpk[q][i] & 0xFFFF0000u);
                    } else {
                        v0 += bmy0; v1 += bmy1;
                    }
                    float p0 = __shfl_xor(v0, 8);
                    float p1 = __shfl_xor(v1, 8);
                    float gi = half ? p0 : v0;
                    float gf = half ? v0 : p0;
                    float gg = half ? p1 : v1;
                    float go = half ? v1 : p1;
                    float cn = sigmoidf_(gf) * creg[q][i] + sigmoidf_(gi) * tanhf(gg);
                    creg[q][i] = cn;
                    float h = sigmoidf_(go) * tanhf(cn);
                    unsigned hb = (unsigned)f2bf(h);
                    unsigned pb = (unsigned)__shfl_xor((int)hb, 1);
                    if (half == 0 && (cc & 1) == 0) {
                        ushort_t* oaddr = Ob + (size_t)n * 1024 + j;
                        unsigned pv = hb | (pb << 16);
                        // no "memory" clobber: data deps order it after the
                        // shfls; volatile order vs the barrier's vmcnt(0).
                        asm volatile("global_store_dword %0, %1, off sc0 sc1"
                                     :: "v"(oaddr), "v"(pv));
                    }
                    if (cl.hlast && half == 0 && t == (int)((lr[q] >> (8*i)) & 0xFF) - 1)
                        cl.hlast[(size_t)n * HDIM + j] = h;
                }
            }
        }
        if (ss < T) {
            asm volatile("s_waitcnt vmcnt(0)" ::: "memory");
            __syncthreads();
            if (tid == 0) {
                __hip_atomic_fetch_add(ctr, 1, __ATOMIC_RELAXED, __HIP_MEMORY_SCOPE_AGENT);
                const int tgt = 128 * (ss + 1);
                int spins = 0;
                while (__hip_atomic_load(ctr, __ATOMIC_RELAXED, __HIP_MEMORY_SCOPE_AGENT) < tgt) {
                    __builtin_amdgcn_s_sleep(1);
                    if (++spins > (1 << 20)) break;
                }
                // acquire: invalidate L1+L2 so cached A-loads see fresh h
                __builtin_amdgcn_fence(__ATOMIC_ACQUIRE, "agent");
            }
            __syncthreads();
        }
    }
}

// ---------------- nz flags ----------------
__global__ __launch_bounds__(64) void nz_kernel(
    const float* __restrict__ he, int* __restrict__ nz)
{
    int rr = blockIdx.x;
    int lane = threadIdx.x;
    const float* row = he + (size_t)rr * HDIM;
    bool any = false;
    for (int k = lane; k < HDIM; k += 64) any |= (row[k] != 0.0f);
    unsigned long long b = __ballot(any);
    if (lane == 0) nz[rr] = (b != 0ull) ? 1 : 0;
}

// ---------------- text_rel expansion ----------------
__global__ __launch_bounds__(256) void expand_kernel(
    const float* __restrict__ he, const int* __restrict__ nz,
    float* __restrict__ out)
{
    int blk = blockIdx.x;               // ((b*10+i)*10+j)*10+k
    int k = blk % 10;
    int j = (blk / 10) % 10;
    int i = (blk / 100) % 10;
    int b = blk / 1000;
    int tid = threadIdx.x;
    float4* o = (float4*)(out + (size_t)blk * 1024);
    float4 z; z.x = z.y = z.z = z.w = 0.0f;
    if (tid < 128) {
        bool m = (j <= i) && (k <= i) && (nz[b*10 + k] != 0);
        float4 v = m ? ((const float4*)(he + (size_t)(b*10 + j) * HDIM))[tid] : z;
        o[tid] = v;
    } else {
        int c = tid - 128;
        bool m = (k <= i) && (j <= i) && (nz[b*10 + j] != 0);
        float4 v = m ? ((const float4*)(he + (size_t)(b*10 + k) * HDIM))[c] : z;
        o[128 + c] = v;
    }
}

extern "C" void kernel_launch(void* const* d_in, const int* in_sizes, int n_in,
                              void* d_out, int out_size, void* d_ws, size_t ws_size,
                              hipStream_t stream)
{
    (void)in_sizes; (void)n_in; (void)out_size; (void)ws_size;
    const int* ques     = (const int*)d_in[0];
    const int* hist     = (const int*)d_in[1];
    const int* ques_len = (const int*)d_in[2];
    const int* hist_len = (const int*)d_in[3];
    const float* w_emb  = (const float*)d_in[6];
    const float* elmo   = (const float*)d_in[7];
    const float* Wc     = (const float*)d_in[8];
    const float* bc     = (const float*)d_in[9];

    // ---- workspace layout ----
    char* ws = (char*)d_ws;
    size_t off = 0;
    auto alloc = [&](size_t bytes) { char* p = ws + off; off += (bytes + 255) & ~(size_t)255; return p; };
    ushort_t* XP0bf = (ushort_t*)alloc((size_t)19200 * G4 * 2);      // 78.6 MB
    ushort_t* Xb    = (ushort_t*)alloc((size_t)19200 * XPAD * 2);    // 32.0 MB
    ushort_t* Wcb   = (ushort_t*)alloc((size_t)HDIM * ELMOD * 2);
    ushort_t *Wih0b[2], *Whh0b[2], *Wcat[2];
    for (int s = 0; s < 2; ++s) {
        Wih0b[s] = (ushort_t*)alloc((size_t)G4 * XPAD * 2);
        Whh0b[s] = (ushort_t*)alloc((size_t)G4 * HDIM * 2);
        Wcat[s]  = (ushort_t*)alloc((size_t)G4 * ELMOD * 2);
    }
    char* state_base = ws + off;
    ushort_t* acat[2][2];
    for (int s = 0; s < 2; ++s)
        for (int p = 0; p < 2; ++p)
            acat[s][p] = (ushort_t*)alloc((size_t)NSEQ * ELMOD * 2);
    int* ctrs = (int*)alloc(256);
    size_t state_bytes = (ws + off) - state_base;
    float* he = (float*)alloc((size_t)NSEQ * HDIM * 4);
    int* nzb  = (int*)alloc(NSEQ * 4);

    float* out = (float*)d_out;
    float* ques_embed = out;
    float* text_rel   = out + (size_t)NSEQ * HDIM;

    const int rowoff[2] = {0, 6400};
    const int TT[2] = {20, 40};
    const int* lensp[2] = {ques_len, hist_len};

    // ---- all weight conversions: one launch ----
    ConvPack CP;
    {
        int ji = 0; long base = 0;
        auto addJob = [&](const float* src, ushort_t* dst, int sc, int ds, int doff, int fc, int rows) {
            CP.src[ji] = src; CP.dst[ji] = dst; CP.srcCols[ji] = sc; CP.dstStride[ji] = ds;
            CP.dstOff[ji] = doff; CP.fillCols[ji] = fc; CP.base[ji] = base;
            base += (long)fc * rows; ++ji;
        };
        addJob(Wc, Wcb, ELMOD, ELMOD, 0, ELMOD, HDIM);
        for (int s = 0; s < 2; ++s) {
            addJob((const float*)d_in[10 + 6*s], Wih0b[s], 812,  XPAD,  0,    XPAD, G4);
            addJob((const float*)d_in[11 + 6*s], Whh0b[s], HDIM, HDIM,  0,    HDIM, G4);
            addJob((const float*)d_in[13 + 6*s], Wcat[s],  HDIM, ELMOD, 0,    HDIM, G4);
            addJob((const float*)d_in[14 + 6*s], Wcat[s],  HDIM, ELMOD, HDIM, HDIM, G4);
        }
        CP.base[9] = base;
        int nblk = (int)((base + 255) / 256);
        conv_all_kernel<<<nblk, 256, 0, stream>>>(CP);
    }

    // ---- embeddings + input projections ----
    emb_gather_kernel<<<19200, 128, 0, stream>>>(ques, hist, w_emb, Xb);
    for (int s = 0; s < 2; ++s) {
        int Ntok = NSEQ * TT[s];
        ushort_t* XbS = Xb + (size_t)rowoff[s] * XPAD;
        const int* tok = s ? hist : ques;
        gemm_ff_kernel<<<dim3(HDIM/64, Ntok/64), 256, 0, stream>>>(
            nullptr, elmo, tok, ELMOD, Wcb, bc, XbS + EMBD, XPAD, ELMOD);
        const float* b0 = (const float*)d_in[12 + 6*s];
        gemm_ff_kernel<<<dim3(G4/64, Ntok/64), 256, 0, stream>>>(
            XbS, nullptr, nullptr, XPAD, Wih0b[s], b0,
            XP0bf + (size_t)rowoff[s] * G4, G4, XPAD);
    }

    // ---- zero recurrent state + barrier counters ----
    hipMemsetAsync(state_base, 0, state_bytes, stream);

    // ---- persistent LSTM: 256 blocks (4 cells x 64, interleaved) ----
    PPack P;
    for (int s = 0; s < 2; ++s) {
        const float* b1 = (const float*)d_in[15 + 6*s];
        PCell& c0 = P.cell[s*2 + 0];
        c0.A0 = acat[s][0]; c0.A1 = acat[s][1];
        c0.B  = Whh0b[s];
        c0.xp = XP0bf + (size_t)rowoff[s] * G4;
        c0.bias = nullptr;
        c0.O0 = acat[s][0]; c0.O1 = acat[s][1];
        c0.hlast = nullptr; c0.lens = lensp[s];
        c0.K = HDIM; c0.T = TT[s]; c0.layer = 0;
        PCell& c1 = P.cell[s*2 + 1];
        c1.A0 = acat[s][0]; c1.A1 = acat[s][1];
        c1.B  = Wcat[s];
        c1.xp = nullptr; c1.bias = b1;
        c1.O0 = acat[s][0] + HDIM; c1.O1 = acat[s][1] + HDIM;
        c1.hlast = s ? he : ques_embed;
        c1.lens = lensp[s];
        c1.K = ELMOD; c1.T = TT[s]; c1.layer = 1;
    }
    lstm_persist_kernel<<<256, 256, 0, stream>>>(P, ctrs);

    // ---- expansion ----
    nz_kernel<<<NSEQ, 64, 0, stream>>>(he, nzb);
    expand_kernel<<<32000, 256, 0, stream>>>(he, nzb, text_rel);
}

// Round 8
// 990.994 us; speedup vs baseline: 1.9130x; 1.2811x over previous
//
#include <hip/hip_runtime.h>
#include <math.h>

#define NSEQ 320
#define HDIM 512
#define G4   2048
#define EMBD 300
#define ELMOD 1024
#define XPAD 832          // 812 padded to multiple of 32
#define BUFU (160*1024)   // ushorts per rotated h step-buffer (160 rows x 1024)

typedef __attribute__((ext_vector_type(8))) short bf16x8;
typedef __attribute__((ext_vector_type(4))) float f32x4;
typedef __attribute__((ext_vector_type(4))) unsigned int u32x4;
typedef __attribute__((ext_vector_type(2))) unsigned int u32x2;
typedef unsigned short ushort_t;

__device__ __forceinline__ float sigmoidf_(float x) { return 1.0f / (1.0f + expf(-x)); }

__device__ __forceinline__ ushort_t f2bf(float f) {
    unsigned u = __float_as_uint(f);
    u = (u + 0x7FFFu + ((u >> 16) & 1u)) >> 16;   // RNE
    return (ushort_t)u;
}
__device__ __forceinline__ unsigned pack2(float a, float b) {
    return (unsigned)f2bf(a) | ((unsigned)f2bf(b) << 16);
}

// ---------------- all weight conversions in ONE flat launch ----------------
struct ConvPack {
    const float* src[9];
    ushort_t* dst[9];
    int srcCols[9], dstStride[9], dstOff[9], fillCols[9];
    long base[10];
};

__global__ __launch_bounds__(256) void conv_all_kernel(ConvPack P)
{
    long gid = (long)blockIdx.x * 256 + threadIdx.x;
    if (gid >= P.base[9]) return;
    int job = 0;
    #pragma unroll
    for (int j = 1; j < 9; ++j) if (gid >= P.base[j]) job = j;
    int e  = (int)(gid - P.base[job]);
    int fc = P.fillCols[job];
    int r  = e / fc;
    int ci = e - r * fc;
    int sc = P.srcCols[job];
    float v = (ci < sc) ? P.src[job][(size_t)r * sc + ci] : 0.0f;
    P.dst[job][(size_t)r * P.dstStride[job] + P.dstOff[job] + ci] = f2bf(v);
}

// ---------------- GloVe gather (ques+hist merged) ----------------
__global__ __launch_bounds__(128) void emb_gather_kernel(
    const int* __restrict__ ques, const int* __restrict__ hist,
    const float* __restrict__ w_emb, ushort_t* __restrict__ Xb)
{
    int n = blockIdx.x;
    int tokid = (n < 6400) ? ques[n] : hist[n - 6400];
    int t = threadIdx.x;
    ushort_t* dst = Xb + (size_t)n * XPAD;
    if (t < 75) {
        const float4* src = (const float4*)(w_emb + (size_t)tokid * EMBD);
        float4 v = src[t];
        dst[4*t+0] = f2bf(v.x); dst[4*t+1] = f2bf(v.y);
        dst[4*t+2] = f2bf(v.z); dst[4*t+3] = f2bf(v.w);
    } else if (t >= 108) {  // 20 pad cols
        dst[812 + (t - 108)] = 0;
    }
}

// ---------------- feed-forward GEMM: C_bf16[M][N] = A[M][K] * W[N][K]^T + bias ----------------
// remap=1: store col' = (col&511)*4 + (col>>9)  (gate-interleaved layout for the LSTM)
__global__ __launch_bounds__(256) void gemm_ff_kernel(
    const ushort_t* __restrict__ Ab, const float* __restrict__ Af,
    const int* __restrict__ tok, int strideA,
    const ushort_t* __restrict__ W, const float* __restrict__ bias,
    ushort_t* __restrict__ C, int strideC, int K, int remap)
{
    __shared__ ushort_t As[64 * 40];
    __shared__ ushort_t Bs[64 * 40];
    const int m0 = blockIdx.y * 64;
    const int n0 = blockIdx.x * 64;
    const int tid = threadIdx.x;
    const int r  = tid >> 2;
    const int kq = (tid & 3) << 3;

    const ushort_t* arow_b = nullptr;
    const float*    arow_f = nullptr;
    if (Af) arow_f = Af + (size_t)tok[m0 + r] * strideA + kq;
    else    arow_b = Ab + (size_t)(m0 + r) * strideA + kq;
    const ushort_t* brow = W + (size_t)(n0 + r) * K + kq;

    const int lane = tid & 63;
    const int w = tid >> 6;
    const int wm = w & 1, wn = w >> 1;
    const int kc = (lane >> 4) << 3;

    f32x4 acc[2][2];
    #pragma unroll
    for (int f = 0; f < 2; ++f)
        #pragma unroll
        for (int g = 0; g < 2; ++g)
            acc[f][g] = (f32x4){0.f, 0.f, 0.f, 0.f};

    for (int k0 = 0; k0 < K; k0 += 32) {
        if (Af) {
            float4 v0 = ((const float4*)(arow_f + k0))[0];
            float4 v1 = ((const float4*)(arow_f + k0))[1];
            uint4 p; p.x = pack2(v0.x, v0.y); p.y = pack2(v0.z, v0.w);
            p.z = pack2(v1.x, v1.y); p.w = pack2(v1.z, v1.w);
            *(uint4*)&As[r*40 + kq] = p;
        } else {
            *(uint4*)&As[r*40 + kq] = *(const uint4*)(arow_b + k0);
        }
        *(uint4*)&Bs[r*40 + kq] = *(const uint4*)(brow + k0);
        __syncthreads();
        bf16x8 af[2], bfr[2];
        #pragma unroll
        for (int f = 0; f < 2; ++f)
            af[f] = *(const bf16x8*)&As[(wm*32 + f*16 + (lane & 15))*40 + kc];
        #pragma unroll
        for (int g = 0; g < 2; ++g)
            bfr[g] = *(const bf16x8*)&Bs[(wn*32 + g*16 + (lane & 15))*40 + kc];
        #pragma unroll
        for (int f = 0; f < 2; ++f)
            #pragma unroll
            for (int g = 0; g < 2; ++g)
                acc[f][g] = __builtin_amdgcn_mfma_f32_16x16x32_bf16(af[f], bfr[g], acc[f][g], 0, 0, 0);
        __syncthreads();
    }

    #pragma unroll
    for (int f = 0; f < 2; ++f) {
        #pragma unroll
        for (int g = 0; g < 2; ++g) {
            int col = n0 + wn*32 + g*16 + (lane & 15);
            float bv = bias[col];
            int colw = remap ? ((col & 511) * 4 + (col >> 9)) : col;
            #pragma unroll
            for (int i = 0; i < 4; ++i) {
                int row = m0 + wm*32 + f*16 + ((lane >> 4) << 2) + i;
                C[(size_t)row * strideC + colw] = f2bf(acc[f][g][i] + bv);
            }
        }
    }
}

// ================= persistent LSTM: 8 instances x 32 blocks =================
struct PCellN {
    ushort_t* rot;          // rotated buffers for (s,v): [41][160][1024]
    const ushort_t* B;      // [2048][K], row = gate*512 + j
    const ushort_t* xp;     // L0: XP0 gate-interleaved, rows pre-offset; null for L1
    const float* bias;      // L1: b1; null L0
    float* hlast;           // L1: fp32 dest (+v*160 rows); null L0
    const int* lens;        // + v*160
    int* lctr;              // intra-instance step counter
    int* pflag;             // per-(s,v) L0 progress flag
    int K, T, layer;
};
struct PPackN { PCellN cell[8]; };

template<int N> __device__ __forceinline__ void vmwait() {
    if constexpr      (N == 0)  asm volatile("s_waitcnt vmcnt(0)"  ::: "memory");
    else if constexpr (N == 1)  asm volatile("s_waitcnt vmcnt(1)"  ::: "memory");
    else if constexpr (N == 2)  asm volatile("s_waitcnt vmcnt(2)"  ::: "memory");
    else if constexpr (N == 3)  asm volatile("s_waitcnt vmcnt(3)"  ::: "memory");
    else if constexpr (N == 4)  asm volatile("s_waitcnt vmcnt(4)"  ::: "memory");
    else if constexpr (N == 5)  asm volatile("s_waitcnt vmcnt(5)"  ::: "memory");
    else if constexpr (N == 6)  asm volatile("s_waitcnt vmcnt(6)"  ::: "memory");
    else if constexpr (N == 7)  asm volatile("s_waitcnt vmcnt(7)"  ::: "memory");
    else if constexpr (N == 8)  asm volatile("s_waitcnt vmcnt(8)"  ::: "memory");
    else if constexpr (N == 9)  asm volatile("s_waitcnt vmcnt(9)"  ::: "memory");
    else if constexpr (N == 10) asm volatile("s_waitcnt vmcnt(10)" ::: "memory");
    else if constexpr (N == 11) asm volatile("s_waitcnt vmcnt(11)" ::: "memory");
    else if constexpr (N == 12) asm volatile("s_waitcnt vmcnt(12)" ::: "memory");
    else if constexpr (N == 13) asm volatile("s_waitcnt vmcnt(13)" ::: "memory");
    else if constexpr (N == 14) asm volatile("s_waitcnt vmcnt(14)" ::: "memory");
    else                        asm volatile("s_waitcnt vmcnt(15)" ::: "memory");
}

// issue chunk C's A-fragment loads (direct global->VGPR, MFMA layout)
template<int C, int NQ, int D>
__device__ __forceinline__ void aissN(uint4 (&ap)[D][NQ],
    const ushort_t* baseX, const ushort_t* baseH, const int* aoff)
{
    const ushort_t* b_ = (C * 32 < 512) ? baseX : baseH;
    #pragma unroll
    for (int q = 0; q < NQ; ++q)
        asm volatile("global_load_dwordx4 %0, %1, off"
            : "=v"(ap[C % D][q])
            : "v"((const char*)b_ + aoff[q] + C * 64));
}

template<int C, int D, int NQ>
__device__ __forceinline__ void prologueN(uint4 (&ap)[D][NQ],
    const ushort_t* bX, const ushort_t* bH, const int* aoff)
{
    if constexpr (C < D) {
        aissN<C, NQ, D>(ap, bX, bH, aoff);
        prologueN<C + 1, D, NQ>(ap, bX, bH, aoff);
    }
}

template<int C, int NC, int NQ, int D>
__device__ __forceinline__ void chunksN(uint4 (&ap)[D][NQ], f32x4 (&acc)[NQ][4],
    const ushort_t* bX, const ushort_t* bH, const int* aoff,
    const ushort_t* Bs, int PK, int cc, int kg)
{
    if constexpr (C < NC) {
        constexpr int infl = (NC - 1 - C) > (D - 1) ? (D - 1) : (NC - 1 - C);
        vmwait<infl * NQ>();
        __builtin_amdgcn_sched_barrier(0);
        bf16x8 bfr[4];
        #pragma unroll
        for (int g = 0; g < 4; ++g)
            bfr[g] = *(const bf16x8*)&Bs[(g*16 + cc)*PK + C*32 + kg*8];
        #pragma unroll
        for (int q = 0; q < NQ; ++q)
            #pragma unroll
            for (int g = 0; g < 4; ++g)
                acc[q][g] = __builtin_amdgcn_mfma_f32_16x16x32_bf16(
                    *(const bf16x8*)&ap[C % D][q], bfr[g], acc[q][g], 0, 0, 0);
        if constexpr (C + D < NC) aissN<C + D, NQ, D>(ap, bX, bH, aoff);
        chunksN<C + 1, NC, NQ, D>(ap, acc, bX, bH, aoff, Bs, PK, cc, kg);
    }
}

template<int NC, int NQ, int D>
__device__ __forceinline__ void step_work(
    const ushort_t* __restrict__ baseX,
    const ushort_t* __restrict__ baseH,
    const ushort_t* __restrict__ Bs, int PK,
    const ushort_t* __restrict__ xp,
    const float* __restrict__ bias_r,
    ushort_t* __restrict__ Ost,
    float* __restrict__ hlast,
    const unsigned* __restrict__ lr,
    float (&creg)[3][4],
    int t, int T, int tq0, int lane, int j)
{
    const int cc = lane & 15, kg = lane >> 4;

    int aoff[NQ];
    #pragma unroll
    for (int q = 0; q < NQ; ++q)
        aoff[q] = ((tq0 + q)*16 + cc)*2048 + kg*16;

    // xp addends (L0): one 8B load = all 4 gates for (n, j). Oldest vm ops ->
    // drained by the k-loop's counted vmcnt waits before any chunk consumes.
    u32x2 xpk[NQ][4];
    if (xp) {
        #pragma unroll
        for (int q = 0; q < NQ; ++q)
            #pragma unroll
            for (int i = 0; i < 4; ++i) {
                const int n = (tq0 + q)*16 + kg*4 + i;
                asm volatile("global_load_dwordx2 %0, %1, off"
                    : "=v"(xpk[q][i])
                    : "v"((const char*)xp + ((size_t)n*T + t)*4096 + (size_t)j*8));
            }
    }

    f32x4 acc[NQ][4];
    #pragma unroll
    for (int q = 0; q < NQ; ++q)
        #pragma unroll
        for (int g = 0; g < 4; ++g)
            acc[q][g] = (f32x4){0.f, 0.f, 0.f, 0.f};

    uint4 ap[D][NQ];
    prologueN<0, D, NQ>(ap, baseX, baseH, aoff);
    chunksN<0, NC, NQ, D>(ap, acc, baseX, baseH, aoff, Bs, PK, cc, kg);
    __builtin_amdgcn_sched_barrier(0);

    #pragma unroll
    for (int q = 0; q < NQ; ++q) {
        const unsigned lq = lr[q];
        #pragma unroll
        for (int i = 0; i < 4; ++i) {
            const int n = (tq0 + q)*16 + kg*4 + i;
            float g0 = acc[q][0][i], g1 = acc[q][1][i];
            float g2 = acc[q][2][i], g3 = acc[q][3][i];
            if (xp) {
                u32x2 xv = xpk[q][i];
                g0 += __uint_as_float(xv.x << 16);
                g1 += __uint_as_float(xv.x & 0xFFFF0000u);
                g2 += __uint_as_float(xv.y << 16);
                g3 += __uint_as_float(xv.y & 0xFFFF0000u);
            } else {
                g0 += bias_r[0]; g1 += bias_r[1];
                g2 += bias_r[2]; g3 += bias_r[3];
            }
            float cn = sigmoidf_(g1) * creg[q][i] + sigmoidf_(g0) * tanhf(g2);
            creg[q][i] = cn;
            float h = sigmoidf_(g3) * tanhf(cn);
            unsigned hb = (unsigned)f2bf(h);
            unsigned pb = (unsigned)__shfl_xor((int)hb, 1);
            if ((cc & 1) == 0) {
                ushort_t* oa = Ost + (size_t)n * 1024 + j;
                asm volatile("global_store_dword %0, %1, off sc0 sc1"
                             :: "v"(oa), "v"(hb | (pb << 16)));
            }
            if (hlast && t == (int)((lq >> (8*i)) & 0xFF) - 1)
                hlast[(size_t)n * HDIM + j] = h;
        }
    }
}

__global__ __launch_bounds__(256) void lstm_persist_kernel(PPackN P)
{
    const int inst = blockIdx.x & 7;      // instance <-> XCD (speed heuristic only)
    const int blk  = blockIdx.x >> 3;     // 0..31 -> j-slice
    const PCellN cl = P.cell[inst];

    const int tid  = threadIdx.x;
    const int w    = tid >> 6;
    const int lane = tid & 63;
    const int cc   = lane & 15;
    const int kg   = lane >> 4;
    const int j0   = blk * 16;
    const int j    = j0 + cc;
    const int K = cl.K, T = cl.T, PK = K + 8;   // PK stride: 2-way banks = free
    const int nq  = (w < 2) ? 3 : 2;            // M-tiles per wave {3,3,2,2} = 160 rows
    const int tq0 = (w < 2) ? w*3 : 6 + (w - 2)*2;

    __shared__ ushort_t Bs[64 * 1032];          // 129 KB max (K=1024)

    // ---- preload B slice (64 gate-rows) into LDS once ----
    {
        const int CH = K >> 3;
        const int tot = 64 * CH;
        for (int idx = tid; idx < tot; idx += 256) {
            int r = idx / CH, ch = idx - r * CH;
            int gr = (r >> 4) * HDIM + j0 + (r & 15);
            *(u32x4*)&Bs[r * PK + ch * 8] = *(const u32x4*)(cl.B + (size_t)gr * K + ch * 8);
        }
    }

    float bias_r[4] = {0.f, 0.f, 0.f, 0.f};
    if (cl.bias) {
        #pragma unroll
        for (int g = 0; g < 4; ++g) bias_r[g] = cl.bias[g * HDIM + j];
    }

    unsigned lr[3] = {0u, 0u, 0u};
    #pragma unroll
    for (int q = 0; q < 3; ++q) {
        if (q < nq) {
            unsigned pkd = 0;
            #pragma unroll
            for (int i = 0; i < 4; ++i)
                pkd |= ((unsigned)cl.lens[(tq0 + q)*16 + kg*4 + i] & 0xFF) << (8*i);
            lr[q] = pkd;
        }
    }

    float creg[3][4];
    #pragma unroll
    for (int q = 0; q < 3; ++q)
        #pragma unroll
        for (int i = 0; i < 4; ++i) creg[q][i] = 0.f;

    __syncthreads();   // B preload visible

    for (int ss = 0; ss <= T; ++ss) {
        const bool active = cl.layer ? (ss >= 1) : (ss < T);
        if (active) {
            const int t = cl.layer ? (ss - 1) : ss;
            const ushort_t* baseX; const ushort_t* baseH; ushort_t* Ost;
            if (cl.layer == 0) {
                baseX = cl.rot + (size_t)t * BUFU;          // own h(t-1), cols 0..511
                baseH = baseX;
                Ost   = cl.rot + (size_t)(t + 1) * BUFU;    // h(t) -> cols 0..511
            } else {
                baseX = cl.rot + (size_t)(t + 1) * BUFU;    // x = L0 h(t), cols 0..511
                baseH = cl.rot + (size_t)t * BUFU;          // own h(t-1), cols 512..1023
                Ost   = cl.rot + (size_t)(t + 1) * BUFU + HDIM;
            }
            if (K == 512) {
                if (w < 2) step_work<16,3,6>(baseX, baseH, Bs, PK, cl.xp, bias_r, Ost, cl.hlast, lr, creg, t, T, tq0, lane, j);
                else       step_work<16,2,8>(baseX, baseH, Bs, PK, cl.xp, bias_r, Ost, cl.hlast, lr, creg, t, T, tq0, lane, j);
            } else {
                if (w < 2) step_work<32,3,6>(baseX, baseH, Bs, PK, cl.xp, bias_r, Ost, cl.hlast, lr, creg, t, T, tq0, lane, j);
                else       step_work<32,2,8>(baseX, baseH, Bs, PK, cl.xp, bias_r, Ost, cl.hlast, lr, creg, t, T, tq0, lane, j);
            }
        }
        if (ss < T) {
            asm volatile("s_waitcnt vmcnt(0)" ::: "memory");  // h stores at coherence point
            __syncthreads();
            if (tid == 0) {
                __hip_atomic_fetch_add(cl.lctr, 1, __ATOMIC_RELAXED, __HIP_MEMORY_SCOPE_AGENT);
                const int tgt = 32 * (ss + 1);
                int spins = 0;
                while (__hip_atomic_load(cl.lctr, __ATOMIC_RELAXED, __HIP_MEMORY_SCOPE_AGENT) < tgt) {
                    __builtin_amdgcn_s_sleep(1);
                    if (++spins > (1 << 20)) break;
                }
                if (cl.layer == 0) {
                    if (blk == 0)
                        __hip_atomic_store(cl.pflag, ss + 1, __ATOMIC_RELAXED, __HIP_MEMORY_SCOPE_AGENT);
                } else {
                    spins = 0;
                    while (__hip_atomic_load(cl.pflag, __ATOMIC_RELAXED, __HIP_MEMORY_SCOPE_AGENT) < ss + 1) {
                        __builtin_amdgcn_s_sleep(1);
                        if (++spins > (1 << 20)) break;
                    }
                }
            }
            __syncthreads();
        }
    }
}

// ---------------- nz flags ----------------
__global__ __launch_bounds__(64) void nz_kernel(
    const float* __restrict__ he, int* __restrict__ nz)
{
    int rr = blockIdx.x;
    int lane = threadIdx.x;
    const float* row = he + (size_t)rr * HDIM;
    bool any = false;
    for (int k = lane; k < HDIM; k += 64) any |= (row[k] != 0.0f);
    unsigned long long b = __ballot(any);
    if (lane == 0) nz[rr] = (b != 0ull) ? 1 : 0;
}

// ---------------- text_rel expansion ----------------
__global__ __launch_bounds__(256) void expand_kernel(
    const float* __restrict__ he, const int* __restrict__ nz,
    float* __restrict__ out)
{
    int blk = blockIdx.x;               // ((b*10+i)*10+j)*10+k
    int k = blk % 10;
    int j = (blk / 10) % 10;
    int i = (blk / 100) % 10;
    int b = blk / 1000;
    int tid = threadIdx.x;
    float4* o = (float4*)(out + (size_t)blk * 1024);
    float4 z; z.x = z.y = z.z = z.w = 0.0f;
    if (tid < 128) {
        bool m = (j <= i) && (k <= i) && (nz[b*10 + k] != 0);
        float4 v = m ? ((const float4*)(he + (size_t)(b*10 + j) * HDIM))[tid] : z;
        o[tid] = v;
    } else {
        int c = tid - 128;
        bool m = (k <= i) && (j <= i) && (nz[b*10 + j] != 0);
        float4 v = m ? ((const float4*)(he + (size_t)(b*10 + k) * HDIM))[c] : z;
        o[128 + c] = v;
    }
}

extern "C" void kernel_launch(void* const* d_in, const int* in_sizes, int n_in,
                              void* d_out, int out_size, void* d_ws, size_t ws_size,
                              hipStream_t stream)
{
    (void)in_sizes; (void)n_in; (void)out_size; (void)ws_size;
    const int* ques     = (const int*)d_in[0];
    const int* hist     = (const int*)d_in[1];
    const int* ques_len = (const int*)d_in[2];
    const int* hist_len = (const int*)d_in[3];
    const float* w_emb  = (const float*)d_in[6];
    const float* elmo   = (const float*)d_in[7];
    const float* Wc     = (const float*)d_in[8];
    const float* bc     = (const float*)d_in[9];

    // ---- workspace layout ----
    char* ws = (char*)d_ws;
    size_t off = 0;
    auto alloc = [&](size_t bytes) { char* p = ws + off; off += (bytes + 255) & ~(size_t)255; return p; };
    ushort_t* XP0bf = (ushort_t*)alloc((size_t)19200 * G4 * 2);      // 78.6 MB

    // union region: Xb (front-end input, dead after XP0 GEMMs) aliases rot buffers
    const size_t rotSlice = (size_t)41 * BUFU * 2;                   // 13.4 MB
    char* uni = alloc(4 * rotSlice);                                 // 53.7 MB >= Xb 32.0 MB
    ushort_t* Xb = (ushort_t*)uni;
    auto rotPtr = [&](int s, int v) { return (ushort_t*)(uni + (size_t)(s*2 + v) * rotSlice); };

    ushort_t* Wcb = (ushort_t*)alloc((size_t)HDIM * ELMOD * 2);
    ushort_t *Wih0b[2], *Whh0b[2], *Wcat[2];
    for (int s = 0; s < 2; ++s) {
        Wih0b[s] = (ushort_t*)alloc((size_t)G4 * XPAD * 2);
        Whh0b[s] = (ushort_t*)alloc((size_t)G4 * HDIM * 2);
        Wcat[s]  = (ushort_t*)alloc((size_t)G4 * ELMOD * 2);
    }
    int* ctrs = (int*)alloc(4096);
    float* he = (float*)alloc((size_t)NSEQ * HDIM * 4);
    int* nzb  = (int*)alloc(NSEQ * 4);

    float* out = (float*)d_out;
    float* ques_embed = out;
    float* text_rel   = out + (size_t)NSEQ * HDIM;

    const int rowoff[2] = {0, 6400};
    const int TT[2] = {20, 40};
    const int* lensp[2] = {ques_len, hist_len};

    // ---- all weight conversions: one launch ----
    ConvPack CP;
    {
        int ji = 0; long base = 0;
        auto addJob = [&](const float* src, ushort_t* dst, int sc, int ds, int doff, int fc, int rows) {
            CP.src[ji] = src; CP.dst[ji] = dst; CP.srcCols[ji] = sc; CP.dstStride[ji] = ds;
            CP.dstOff[ji] = doff; CP.fillCols[ji] = fc; CP.base[ji] = base;
            base += (long)fc * rows; ++ji;
        };
        addJob(Wc, Wcb, ELMOD, ELMOD, 0, ELMOD, HDIM);
        for (int s = 0; s < 2; ++s) {
            addJob((const float*)d_in[10 + 6*s], Wih0b[s], 812,  XPAD,  0,    XPAD, G4);
            addJob((const float*)d_in[11 + 6*s], Whh0b[s], HDIM, HDIM,  0,    HDIM, G4);
            addJob((const float*)d_in[13 + 6*s], Wcat[s],  HDIM, ELMOD, 0,    HDIM, G4);
            addJob((const float*)d_in[14 + 6*s], Wcat[s],  HDIM, ELMOD, HDIM, HDIM, G4);
        }
        CP.base[9] = base;
        int nblk = (int)((base + 255) / 256);
        conv_all_kernel<<<nblk, 256, 0, stream>>>(CP);
    }

    // ---- embeddings + input projections (read Xb BEFORE rot aliasing) ----
    emb_gather_kernel<<<19200, 128, 0, stream>>>(ques, hist, w_emb, Xb);
    for (int s = 0; s < 2; ++s) {
        int Ntok = NSEQ * TT[s];
        ushort_t* XbS = Xb + (size_t)rowoff[s] * XPAD;
        const int* tok = s ? hist : ques;
        gemm_ff_kernel<<<dim3(HDIM/64, Ntok/64), 256, 0, stream>>>(
            nullptr, elmo, tok, ELMOD, Wcb, bc, XbS + EMBD, XPAD, ELMOD, 0);
        const float* b0 = (const float*)d_in[12 + 6*s];
        gemm_ff_kernel<<<dim3(G4/64, Ntok/64), 256, 0, stream>>>(
            XbS, nullptr, nullptr, XPAD, Wih0b[s], b0,
            XP0bf + (size_t)rowoff[s] * G4, G4, XPAD, 1);   // gate-interleaved
    }

    // ---- zero rot[0] (h(-1)=0) + counters; AFTER Xb consumed (aliased) ----
    hipMemsetAsync(ctrs, 0, 4096, stream);
    for (int s = 0; s < 2; ++s)
        for (int v = 0; v < 2; ++v)
            hipMemsetAsync(rotPtr(s, v), 0, (size_t)BUFU * 2, stream);

    // ---- persistent LSTM: 256 blocks = 8 instances x 32 j-slices ----
    PPackN P;
    for (int layer = 0; layer < 2; ++layer)
        for (int s = 0; s < 2; ++s)
            for (int v = 0; v < 2; ++v) {
                PCellN& c = P.cell[layer*4 + s*2 + v];
                c.rot   = rotPtr(s, v);
                c.B     = layer ? Wcat[s] : Whh0b[s];
                c.xp    = layer ? nullptr
                                : XP0bf + (size_t)(rowoff[s] + v*160*TT[s]) * G4;
                c.bias  = layer ? (const float*)d_in[15 + 6*s] : nullptr;
                c.hlast = layer ? ((s ? he : ques_embed) + (size_t)v*160*HDIM) : nullptr;
                c.lens  = lensp[s] + v*160;
                c.lctr  = ctrs + (layer*4 + s*2 + v) * 64;
                c.pflag = ctrs + 512 + (s*2 + v) * 64;
                c.K = layer ? ELMOD : HDIM;
                c.T = TT[s];
                c.layer = layer;
            }
    lstm_persist_kernel<<<256, 256, 0, stream>>>(P);

    // ---- expansion ----
    nz_kernel<<<NSEQ, 64, 0, stream>>>(he, nzb);
    expand_kernel<<<32000, 256, 0, stream>>>(he, nzb, text_rel);
}